// Round 3
// baseline (4734.246 us; speedup 1.0000x reference)
//
#include <hip/hip_runtime.h>
#include <hip/hip_bf16.h>

#define B_ 4
#define N_ 8192
#define D_ 512
#define H_ 8
#define DH_ 64
#define M_ 256
#define LCH 32
#define KER_ 33

typedef __hip_bfloat16 bf16;

__device__ __forceinline__ float bf2f(bf16 h){ return __bfloat162float(h); }
__device__ __forceinline__ bf16 f2bf(float f){ return __float2bfloat16(f); }

// ---------------- LayerNorm: x (b,n,512) fp32 -> xn bf16 ----------------
__global__ __launch_bounds__(256) void k_layernorm(const float* __restrict__ x,
    const float* __restrict__ gamma, const float* __restrict__ beta,
    bf16* __restrict__ xn){
  int row = blockIdx.x;                       // 32768 rows
  const float* xr = x + (size_t)row * D_;
  bf16* o = xn + (size_t)row * D_;
  int t = threadIdx.x;                        // 256
  float v0 = xr[t], v1 = xr[t+256];
  float s = v0+v1, ss = v0*v0 + v1*v1;
  __shared__ float sh[8];
  for (int off=32; off; off>>=1){ s += __shfl_xor(s,off); ss += __shfl_xor(ss,off); }
  int lane = t&63, wid = t>>6;
  if (lane==0){ sh[wid] = s; sh[wid+4] = ss; }
  __syncthreads();
  float S  = sh[0]+sh[1]+sh[2]+sh[3];
  float SS = sh[4]+sh[5]+sh[6]+sh[7];
  float mu = S*(1.f/D_);
  float var = SS*(1.f/D_) - mu*mu;
  float rs = rsqrtf(var + 1e-5f);
  o[t]     = f2bf((v0-mu)*rs*gamma[t]     + beta[t]);
  o[t+256] = f2bf((v1-mu)*rs*gamma[t+256] + beta[t+256]);
}

// ---------------- QKV GEMM: xn(32768x512)bf16 @ w_qkv(512x1536)fp32, scatter head-major bf16 ----------------
__global__ __launch_bounds__(256) void k_gemm_qkv(const bf16* __restrict__ A, const float* __restrict__ W,
    bf16* __restrict__ qbuf, bf16* __restrict__ kbuf, bf16* __restrict__ vbuf){
  __shared__ float As[16][68];
  __shared__ float Bs[16][64];
  int t = threadIdx.x, tx = t&15, ty = t>>4;
  int r0 = blockIdx.x*64, c0 = blockIdx.y*64;
  float acc[4][4] = {};
  for (int k0=0; k0<D_; k0+=16){
    for (int i=t; i<1024; i+=256){
      int m = i>>4, kq = i&15;
      As[kq][m] = bf2f(A[(size_t)(r0+m)*D_ + k0+kq]);
      int nn = i&63, k2 = i>>6;
      Bs[k2][nn] = W[(size_t)(k0+k2)*1536 + c0+nn];
    }
    __syncthreads();
    #pragma unroll
    for (int kq=0;kq<16;kq++){
      float a0[4], b0[4];
      #pragma unroll
      for (int i=0;i<4;i++) a0[i] = As[kq][ty*4+i];
      #pragma unroll
      for (int j=0;j<4;j++) b0[j] = Bs[kq][tx*4+j];
      #pragma unroll
      for (int i=0;i<4;i++)
        #pragma unroll
        for (int j=0;j<4;j++) acc[i][j] += a0[i]*b0[j];
    }
    __syncthreads();
  }
  int part = c0 >> 9;                          // 0=q 1=k 2=v (uniform per block)
  bf16* dstbuf = (part==0)? qbuf : (part==1)? kbuf : vbuf;
  float scale = (part==0)? 0.125f : 1.f;       // DH^-0.5
  #pragma unroll
  for (int i=0;i<4;i++){
    int r = r0 + ty*4 + i;
    int b = r >> 13, n = r & 8191;
    #pragma unroll
    for (int j=0;j<4;j++){
      int c = c0 + tx*4 + j;
      int cc = c & 511;
      int h = cc >> 6, dh = cc & 63;
      dstbuf[(((size_t)(b*H_+h))*N_ + n)*DH_ + dh] = f2bf(acc[i][j]*scale);
    }
  }
}

// ---------------- landmark means over contiguous 32-row chunks ----------------
__global__ __launch_bounds__(64) void k_landmark(const bf16* __restrict__ q, const bf16* __restrict__ k,
    bf16* __restrict__ ql, bf16* __restrict__ kl){
  int bhm = blockIdx.x;                        // 32*256
  int bh = bhm >> 8, m = bhm & 255;
  int dh = threadIdx.x;
  const bf16* qp = q + ((size_t)bh*N_ + (size_t)m*LCH)*DH_ + dh;
  const bf16* kp = k + ((size_t)bh*N_ + (size_t)m*LCH)*DH_ + dh;
  float sq=0.f, sk=0.f;
  #pragma unroll
  for (int j=0;j<LCH;j++){ sq += bf2f(qp[(size_t)j*DH_]); sk += bf2f(kp[(size_t)j*DH_]); }
  ql[((size_t)bh*M_ + m)*DH_ + dh] = f2bf(sq*(1.f/LCH));
  kl[((size_t)bh*M_ + m)*DH_ + dh] = f2bf(sk*(1.f/LCH));
}

// ---------------- attn2 = softmax(q_l @ k_l^T) rows (fp32 out) ----------------
__global__ __launch_bounds__(256) void k_attn2(const bf16* __restrict__ ql, const bf16* __restrict__ kl,
    float* __restrict__ A2){
  int bhm = blockIdx.x;                        // 8192
  int bh = bhm >> 8, m = bhm & 255;
  int t = threadIdx.x;
  __shared__ float qrow[64];
  __shared__ float sh[4];
  if (t < 64) qrow[t] = bf2f(ql[((size_t)bh*M_ + m)*DH_ + t]);
  __syncthreads();
  const bf16* krow = kl + ((size_t)bh*M_ + t)*DH_;
  float s = 0.f;
  #pragma unroll
  for (int i=0;i<64;i++) s += qrow[i]*bf2f(krow[i]);
  float mx = s;
  for (int off=32; off; off>>=1) mx = fmaxf(mx, __shfl_xor(mx, off));
  if ((t&63)==0) sh[t>>6] = mx;
  __syncthreads();
  mx = fmaxf(fmaxf(sh[0],sh[1]), fmaxf(sh[2],sh[3]));
  float e = expf(s - mx);
  float sum = e;
  for (int off=32; off; off>>=1) sum += __shfl_xor(sum, off);
  __syncthreads();
  if ((t&63)==0) sh[t>>6] = sum;
  __syncthreads();
  sum = sh[0]+sh[1]+sh[2]+sh[3];
  A2[((size_t)bh*M_ + m)*M_ + t] = e/sum;
}

// ---------------- pinv init: Z = A^T / (max_rowsum * max_colsum) ----------------
__global__ __launch_bounds__(256) void k_pinv_init(const float* __restrict__ A2, float* __restrict__ Z){
  int bh = blockIdx.x;
  int t = threadIdx.x;
  const float* Ab = A2 + (size_t)bh*M_*M_;
  float* Zb = Z + (size_t)bh*M_*M_;
  float cs=0.f, rsm=0.f;
  for (int r=0;r<M_;r++) cs += fabsf(Ab[(size_t)r*M_ + t]);
  for (int c=0;c<M_;c++) rsm += fabsf(Ab[(size_t)t*M_ + c]);
  __shared__ float sh[4];
  float v = cs;
  for (int off=32; off; off>>=1) v = fmaxf(v, __shfl_xor(v, off));
  if ((t&63)==0) sh[t>>6] = v;
  __syncthreads();
  float maxc = fmaxf(fmaxf(sh[0],sh[1]), fmaxf(sh[2],sh[3]));
  __syncthreads();
  v = rsm;
  for (int off=32; off; off>>=1) v = fmaxf(v, __shfl_xor(v, off));
  if ((t&63)==0) sh[t>>6] = v;
  __syncthreads();
  float maxr = fmaxf(fmaxf(sh[0],sh[1]), fmaxf(sh[2],sh[3]));
  float inv = 1.f/(maxr*maxc);
  for (int r=0;r<M_;r++) Zb[(size_t)r*M_ + t] = Ab[(size_t)t*M_ + r]*inv;   // Z = A^T * inv
}

// ---------------- out = a*I - X (elementwise, per bh 256x256) ----------------
__global__ __launch_bounds__(256) void k_aI_minus(float* __restrict__ out, const float* __restrict__ X, float aa){
  size_t i = (size_t)blockIdx.x*256 + threadIdx.x;
  int within = (int)(i & (size_t)(M_*M_-1));
  int r = within >> 8, c = within & 255;
  out[i] = ((r==c)? aa : 0.f) - X[i];
}

// ---------------- batched GEMM 256x256x256 fp32, C = scale*A@B ----------------
__global__ __launch_bounds__(256) void k_gemm_p(float* __restrict__ C, const float* __restrict__ A,
    const float* __restrict__ Bm, float scale){
  int bh = blockIdx.y;
  int tm = blockIdx.x >> 2, tn = blockIdx.x & 3;
  const float* Ab = A  + (size_t)bh*65536;
  const float* Bb = Bm + (size_t)bh*65536;
  float* Cb = C + (size_t)bh*65536;
  __shared__ float As[16][68];
  __shared__ float Bs[16][64];
  int t = threadIdx.x, tx = t&15, ty = t>>4;
  int r0 = tm*64, c0 = tn*64;
  float acc[4][4] = {};
  for (int k0=0;k0<256;k0+=16){
    for (int i=t;i<1024;i+=256){
      int m=i>>4, kq=i&15;
      As[kq][m] = Ab[(size_t)(r0+m)*256 + k0+kq];
      int nn=i&63, k2=i>>6;
      Bs[k2][nn] = Bb[(size_t)(k0+k2)*256 + c0+nn];
    }
    __syncthreads();
    #pragma unroll
    for (int kq=0;kq<16;kq++){
      float a0[4], b0[4];
      #pragma unroll
      for (int i=0;i<4;i++) a0[i] = As[kq][ty*4+i];
      #pragma unroll
      for (int j=0;j<4;j++) b0[j] = Bs[kq][tx*4+j];
      #pragma unroll
      for (int i=0;i<4;i++)
        #pragma unroll
        for (int j=0;j<4;j++) acc[i][j] += a0[i]*b0[j];
    }
    __syncthreads();
  }
  #pragma unroll
  for (int i=0;i<4;i++){
    int r = r0+ty*4+i;
    #pragma unroll
    for (int j=0;j<4;j++)
      Cb[(size_t)r*256 + c0+tx*4+j] = acc[i][j]*scale;
  }
}

// ---------------- batched GEMM 256x64x256: z2(bf16) = Z(fp32) @ kv3(bf16) ----------------
__global__ __launch_bounds__(256) void k_gemm_z2(bf16* __restrict__ C, const float* __restrict__ A,
    const bf16* __restrict__ Bm){
  int bh = blockIdx.y;
  int tm = blockIdx.x;                           // 0..3
  const float* Ab = A  + (size_t)bh*65536;
  const bf16* Bb = Bm + (size_t)bh*M_*DH_;
  bf16* Cb = C + (size_t)bh*M_*DH_;
  __shared__ float As[16][68];
  __shared__ float Bs[16][64];
  int t = threadIdx.x, tx = t&15, ty = t>>4;
  int r0 = tm*64;
  float acc[4][4] = {};
  for (int k0=0;k0<256;k0+=16){
    for (int i=t;i<1024;i+=256){
      int m=i>>4, kq=i&15;
      As[kq][m] = Ab[(size_t)(r0+m)*256 + k0+kq];
      int nn=i&63, k2=i>>6;
      Bs[k2][nn] = bf2f(Bb[(size_t)(k0+k2)*64 + nn]);
    }
    __syncthreads();
    #pragma unroll
    for (int kq=0;kq<16;kq++){
      float a0[4], b0[4];
      #pragma unroll
      for (int i=0;i<4;i++) a0[i] = As[kq][ty*4+i];
      #pragma unroll
      for (int j=0;j<4;j++) b0[j] = Bs[kq][tx*4+j];
      #pragma unroll
      for (int i=0;i<4;i++)
        #pragma unroll
        for (int j=0;j<4;j++) acc[i][j] += a0[i]*b0[j];
    }
    __syncthreads();
  }
  #pragma unroll
  for (int i=0;i<4;i++){
    int r = r0+ty*4+i;
    #pragma unroll
    for (int j=0;j<4;j++)
      Cb[(size_t)r*64 + tx*4+j] = f2bf(acc[i][j]);
  }
}

// ---------------- flash: O = softmax_cols(Q K^T) @ V, bf16 in/out, fp32 inside ----------------
template<int ROWS>
__global__ __launch_bounds__(256) void k_flash_av(const bf16* __restrict__ Q, const bf16* __restrict__ Km,
    const bf16* __restrict__ V, bf16* __restrict__ O, int nrows, int ncols){
  int bh = blockIdx.y;
  int r0 = blockIdx.x * ROWS;
  const size_t qoff = ((size_t)bh*nrows + r0)*DH_;
  const size_t koff = (size_t)bh*(size_t)ncols*DH_;
  __shared__ float qs[ROWS][64];
  __shared__ float ks[64][65];
  __shared__ float vs[64][64];
  __shared__ float sc[ROWS][65];
  __shared__ float accs[ROWS][64];
  __shared__ float mx[ROWS], sm[ROWS], scl[ROWS];
  int t = threadIdx.x;
  for (int i=t;i<ROWS*64;i+=256){ qs[i>>6][i&63] = bf2f(Q[qoff+i]); accs[i>>6][i&63] = 0.f; }
  if (t < ROWS){ mx[t] = -1e30f; sm[t] = 0.f; }
  __syncthreads();
  int c = t & 63, g = t >> 6;
  int ntiles = ncols >> 6;
  for (int tile=0; tile<ntiles; ++tile){
    const bf16* kp = Km + koff + (size_t)tile*64*DH_;
    const bf16* vp = V  + koff + (size_t)tile*64*DH_;
    for (int i=t;i<4096;i+=256){ ks[i>>6][i&63] = bf2f(kp[i]); vs[i>>6][i&63] = bf2f(vp[i]); }
    __syncthreads();
    #pragma unroll
    for (int rr=g; rr<ROWS; rr+=4){
      float a = 0.f;
      #pragma unroll
      for (int i=0;i<64;i++) a += qs[rr][i]*ks[c][i];
      sc[rr][c] = a;
    }
    __syncthreads();
    if (t < ROWS){
      float mo = mx[t], mn = mo;
      for (int ccx=0;ccx<64;ccx++) mn = fmaxf(mn, sc[t][ccx]);
      float alpha = expf(mo - mn);
      float ssum = 0.f;
      for (int ccx=0;ccx<64;ccx++){ float e = expf(sc[t][ccx]-mn); sc[t][ccx] = e; ssum += e; }
      mx[t] = mn; sm[t] = sm[t]*alpha + ssum; scl[t] = alpha;
    }
    __syncthreads();
    #pragma unroll
    for (int rr=g; rr<ROWS; rr+=4){
      float a = accs[rr][c]*scl[rr];
      #pragma unroll
      for (int ccx=0;ccx<64;ccx++) a += sc[rr][ccx]*vs[ccx][c];
      accs[rr][c] = a;
    }
    __syncthreads();
  }
  for (int i=t;i<ROWS*64;i+=256){ int rr=i>>6; O[qoff+i] = f2bf(accs[rr][i&63]/sm[rr]); }
}

// ---------------- depthwise conv(KER=33) over sequence on v, add into outh (bf16 rmw) ----------------
__global__ __launch_bounds__(256) void k_conv_add(const bf16* __restrict__ v, const float* __restrict__ w,
    bf16* __restrict__ outh){
  size_t gid = (size_t)blockIdx.x*256 + threadIdx.x;
  int dh = (int)(gid & 63);
  int n  = (int)((gid >> 6) & (size_t)(N_-1));
  int bh = (int)(gid >> 19);
  int h = bh & 7;
  __shared__ float wk[KER_];
  if (threadIdx.x < KER_) wk[threadIdx.x] = w[h*KER_ + threadIdx.x];
  __syncthreads();
  const bf16* vb = v + (size_t)bh*N_*DH_;
  float acc = bf2f(outh[gid]);
  #pragma unroll
  for (int tt=0; tt<KER_; tt++){
    int nn = n + tt - 16;
    if (nn >= 0 && nn < N_) acc += wk[tt]*bf2f(vb[(size_t)nn*DH_ + dh]);
  }
  outh[gid] = f2bf(acc);
}

// ---------------- final: out = x + gather(outh) @ w_out + b_out (fp32 out) ----------------
__global__ __launch_bounds__(256) void k_gemm_out(const bf16* __restrict__ Ah, const float* __restrict__ W,
    const float* __restrict__ bias, const float* __restrict__ xin, float* __restrict__ out){
  __shared__ float As[16][68];
  __shared__ float Bs[16][64];
  int t = threadIdx.x, tx = t&15, ty = t>>4;
  int r0 = blockIdx.x*64, c0 = blockIdx.y*64;
  int b = r0 >> 13;
  int nbase = r0 & 8191;
  float acc[4][4] = {};
  for (int k0=0;k0<512;k0+=16){
    int h = k0 >> 6;                    // uniform: k0 mult of 16, slice stays in one head
    int dh0 = k0 & 63;
    const bf16* Ab = Ah + ((size_t)(b*H_+h)*N_)*DH_;
    for (int i=t;i<1024;i+=256){
      int m=i>>4, kq=i&15;
      As[kq][m] = bf2f(Ab[(size_t)(nbase+m)*DH_ + dh0+kq]);
      int nn=i&63, k2=i>>6;
      Bs[k2][nn] = W[(size_t)(k0+k2)*512 + c0+nn];
    }
    __syncthreads();
    #pragma unroll
    for (int kq=0;kq<16;kq++){
      float a0[4], b0[4];
      #pragma unroll
      for (int i=0;i<4;i++) a0[i] = As[kq][ty*4+i];
      #pragma unroll
      for (int j=0;j<4;j++) b0[j] = Bs[kq][tx*4+j];
      #pragma unroll
      for (int i=0;i<4;i++)
        #pragma unroll
        for (int j=0;j<4;j++) acc[i][j] += a0[i]*b0[j];
    }
    __syncthreads();
  }
  #pragma unroll
  for (int i=0;i<4;i++){
    int r = r0+ty*4+i;
    #pragma unroll
    for (int j=0;j<4;j++){
      int c = c0+tx*4+j;
      out[(size_t)r*512 + c] = acc[i][j] + bias[c] + xin[(size_t)r*512 + c];
    }
  }
}

extern "C" void kernel_launch(void* const* d_in, const int* in_sizes, int n_in,
                              void* d_out, int out_size, void* d_ws, size_t ws_size,
                              hipStream_t stream) {
  const float* x     = (const float*)d_in[0];
  const float* gamma = (const float*)d_in[1];
  const float* beta  = (const float*)d_in[2];
  const float* wqkv  = (const float*)d_in[3];
  const float* resk  = (const float*)d_in[4];
  const float* wout  = (const float*)d_in[5];
  const float* bout  = (const float*)d_in[6];
  float* out = (float*)d_out;

  const size_t SL = (size_t)B_*H_*N_*DH_;     // 16,777,216
  const size_t SM = (size_t)B_*H_*M_*DH_;     // 524,288
  const size_t SP = (size_t)B_*H_*M_*M_;      // 2,097,152

  // bf16 region: xn(+outh reuse), q, k, v, ql, kl, kv3, z2
  bf16* xn  = (bf16*)d_ws;     // reused as outh after qkv GEMM
  bf16* q   = xn + SL;
  bf16* k   = q + SL;
  bf16* v   = k + SL;
  bf16* ql  = v + SL;
  bf16* kl  = ql + SM;
  bf16* kv3 = kl + SM;
  bf16* z2  = kv3 + SM;
  // fp32 region: pinv chain (exactly mirrors reference fp32 op order)
  float* A2 = (float*)(z2 + SM);
  float* P1 = A2 + SP;
  float* P2 = P1 + SP;
  float* P3 = P2 + SP;
  float* P4 = P3 + SP;        // total ~172 MiB

  k_layernorm<<<B_*N_, 256, 0, stream>>>(x, gamma, beta, xn);
  k_gemm_qkv<<<dim3(512, 24), 256, 0, stream>>>(xn, wqkv, q, k, v);
  k_landmark<<<B_*H_*M_, 64, 0, stream>>>(q, k, ql, kl);
  k_attn2<<<B_*H_*M_, 256, 0, stream>>>(ql, kl, A2);
  k_pinv_init<<<B_*H_, 256, 0, stream>>>(A2, P1);

  float* Z = P1; float* X = P2; float* T = P3; float* U = P4;
  for (int it=0; it<6; ++it){
    k_gemm_p<<<dim3(16,32), 256, 0, stream>>>(X, A2, Z, 1.f);   // X = A@Z
    k_aI_minus<<<8192, 256, 0, stream>>>(T, X, 7.f);            // T = 7I - X
    k_gemm_p<<<dim3(16,32), 256, 0, stream>>>(U, X, T, 1.f);    // U = X@T
    k_aI_minus<<<8192, 256, 0, stream>>>(U, U, 15.f);           // U = 15I - U
    k_gemm_p<<<dim3(16,32), 256, 0, stream>>>(T, X, U, 1.f);    // T = X@U
    k_aI_minus<<<8192, 256, 0, stream>>>(T, T, 13.f);           // T = 13I - T
    k_gemm_p<<<dim3(16,32), 256, 0, stream>>>(X, Z, T, 0.25f);  // Znew = 0.25*Z@T
    float* tmp = Z; Z = X; X = tmp;
  }

  // kv3 = softmax(q_l k^T) @ v   (attn3 @ v), flash over N
  k_flash_av<16><<<dim3(M_/16, B_*H_), 256, 0, stream>>>(ql, k, v, kv3, M_, N_);
  // z2 = pinv(attn2) @ kv3
  k_gemm_z2<<<dim3(4, B_*H_), 256, 0, stream>>>(z2, Z, kv3);
  // outh = softmax(q k_l^T) @ z2  (attn1 @ z2), flash over M — writes into xn buffer
  k_flash_av<16><<<dim3(N_/16, B_*H_), 256, 0, stream>>>(q, kl, z2, xn, N_, M_);
  // + depthwise conv of v
  k_conv_add<<<(int)(SL/256), 256, 0, stream>>>(v, resk, xn);
  // out = x + outh @ w_out + b_out
  k_gemm_out<<<dim3(512, 8), 256, 0, stream>>>(xn, wout, bout, x, out);
}

// Round 4
// 1947.982 us; speedup vs baseline: 2.4303x; 2.4303x over previous
//
#include <hip/hip_runtime.h>
#include <hip/hip_bf16.h>

#define B_ 4
#define N_ 8192
#define D_ 512
#define H_ 8
#define DH_ 64
#define M_ 256
#define LCH 32
#define KER_ 33

typedef __hip_bfloat16 bf16;
typedef __attribute__((ext_vector_type(8))) short short8;
typedef __attribute__((ext_vector_type(4))) float f32x4;

__device__ __forceinline__ float bf2f(bf16 h){ return __bfloat162float(h); }
__device__ __forceinline__ bf16 f2bf(float f){ return __float2bfloat16(f); }
__device__ __forceinline__ f32x4 mfma16(short8 a, short8 b, f32x4 c){
  return __builtin_amdgcn_mfma_f32_16x16x32_bf16(a, b, c, 0, 0, 0);
}

// ---------------- LayerNorm: x (b,n,512) fp32 -> xn bf16 ----------------
__global__ __launch_bounds__(256) void k_layernorm(const float* __restrict__ x,
    const float* __restrict__ gamma, const float* __restrict__ beta,
    bf16* __restrict__ xn){
  int row = blockIdx.x;
  const float* xr = x + (size_t)row * D_;
  bf16* o = xn + (size_t)row * D_;
  int t = threadIdx.x;
  float v0 = xr[t], v1 = xr[t+256];
  float s = v0+v1, ss = v0*v0 + v1*v1;
  __shared__ float sh[8];
  for (int off=32; off; off>>=1){ s += __shfl_xor(s,off); ss += __shfl_xor(ss,off); }
  int lane = t&63, wid = t>>6;
  if (lane==0){ sh[wid] = s; sh[wid+4] = ss; }
  __syncthreads();
  float S  = sh[0]+sh[1]+sh[2]+sh[3];
  float SS = sh[4]+sh[5]+sh[6]+sh[7];
  float mu = S*(1.f/D_);
  float var = SS*(1.f/D_) - mu*mu;
  float rs = rsqrtf(var + 1e-5f);
  o[t]     = f2bf((v0-mu)*rs*gamma[t]     + beta[t]);
  o[t+256] = f2bf((v1-mu)*rs*gamma[t+256] + beta[t+256]);
}

// ---------------- QKV GEMM (MFMA): xn(32768x512)bf16 @ wqkv(512x1536)fp32 -> q,k,v,vT bf16 ----------------
__global__ __launch_bounds__(256) void k_mm_qkv(const bf16* __restrict__ A, const float* __restrict__ W,
    bf16* __restrict__ qbuf, bf16* __restrict__ kbuf, bf16* __restrict__ vbuf, bf16* __restrict__ vtbuf){
  __shared__ __align__(16) bf16 bt[128][40];
  int t = threadIdx.x;
  int w = t>>6, lane = t&63, qd = lane>>4, n = lane&15;
  int r0 = blockIdx.x*64, c0 = blockIdx.y*128;
  f32x4 acc[8];
  #pragma unroll
  for (int i=0;i<8;i++) acc[i] = (f32x4){0.f,0.f,0.f,0.f};
  for (int k0=0; k0<512; k0+=32){
    for (int i=t;i<4096;i+=256){
      int kk = i>>7, cc = i&127;
      bt[cc][kk] = f2bf(W[(size_t)(k0+kk)*1536 + c0+cc]);
    }
    __syncthreads();
    short8 a = *(const short8*)&A[(size_t)(r0 + w*16 + n)*512 + k0 + qd*8];
    #pragma unroll
    for (int nt=0; nt<8; nt++){
      short8 b = *(const short8*)&bt[nt*16+n][qd*8];
      acc[nt] = mfma16(a, b, acc[nt]);
    }
    __syncthreads();
  }
  int part = c0 >> 9;
  bf16* dst = (part==0)? qbuf : (part==1)? kbuf : vbuf;
  float scale = (part==0)? 0.125f : 1.f;
  #pragma unroll
  for (int nt=0; nt<8; nt++){
    int c = c0 + nt*16 + n;
    int cc = c & 511, h = cc>>6, dh = cc&63;
    #pragma unroll
    for (int rg=0; rg<4; rg++){
      int r = r0 + w*16 + qd*4 + rg;
      int b = r >> 13, nn = r & 8191;
      float val = acc[nt][rg]*scale;
      dst[(((size_t)(b*H_+h))*N_ + nn)*DH_ + dh] = f2bf(val);
      if (part==2) vtbuf[(((size_t)(b*H_+h))*DH_ + dh)*N_ + nn] = f2bf(val);
    }
  }
}

// ---------------- landmark means over contiguous 32-row chunks ----------------
__global__ __launch_bounds__(64) void k_landmark(const bf16* __restrict__ q, const bf16* __restrict__ k,
    bf16* __restrict__ ql, bf16* __restrict__ kl){
  int bhm = blockIdx.x;
  int bh = bhm >> 8, m = bhm & 255;
  int dh = threadIdx.x;
  const bf16* qp = q + ((size_t)bh*N_ + (size_t)m*LCH)*DH_ + dh;
  const bf16* kp = k + ((size_t)bh*N_ + (size_t)m*LCH)*DH_ + dh;
  float sq=0.f, sk=0.f;
  #pragma unroll
  for (int j=0;j<LCH;j++){ sq += bf2f(qp[(size_t)j*DH_]); sk += bf2f(kp[(size_t)j*DH_]); }
  ql[((size_t)bh*M_ + m)*DH_ + dh] = f2bf(sq*(1.f/LCH));
  kl[((size_t)bh*M_ + m)*DH_ + dh] = f2bf(sk*(1.f/LCH));
}

// ---------------- attn2 = softmax(q_l @ k_l^T) rows (fp32 out) ----------------
__global__ __launch_bounds__(256) void k_attn2(const bf16* __restrict__ ql, const bf16* __restrict__ kl,
    float* __restrict__ A2){
  int bhm = blockIdx.x;
  int bh = bhm >> 8, m = bhm & 255;
  int t = threadIdx.x;
  __shared__ float qrow[64];
  __shared__ float sh[4];
  if (t < 64) qrow[t] = bf2f(ql[((size_t)bh*M_ + m)*DH_ + t]);
  __syncthreads();
  const bf16* krow = kl + ((size_t)bh*M_ + t)*DH_;
  float s = 0.f;
  #pragma unroll
  for (int i=0;i<64;i++) s += qrow[i]*bf2f(krow[i]);
  float mx = s;
  for (int off=32; off; off>>=1) mx = fmaxf(mx, __shfl_xor(mx, off));
  if ((t&63)==0) sh[t>>6] = mx;
  __syncthreads();
  mx = fmaxf(fmaxf(sh[0],sh[1]), fmaxf(sh[2],sh[3]));
  float e = expf(s - mx);
  float sum = e;
  for (int off=32; off; off>>=1) sum += __shfl_xor(sum, off);
  __syncthreads();
  if ((t&63)==0) sh[t>>6] = sum;
  __syncthreads();
  sum = sh[0]+sh[1]+sh[2]+sh[3];
  A2[((size_t)bh*M_ + m)*M_ + t] = e/sum;
}

// ---------------- pinv init: Z = A^T / (max_rowsum * max_colsum) ----------------
__global__ __launch_bounds__(256) void k_pinv_init(const float* __restrict__ A2, float* __restrict__ Z){
  int bh = blockIdx.x;
  int t = threadIdx.x;
  const float* Ab = A2 + (size_t)bh*M_*M_;
  float* Zb = Z + (size_t)bh*M_*M_;
  float cs=0.f, rsm=0.f;
  for (int r=0;r<M_;r++) cs += fabsf(Ab[(size_t)r*M_ + t]);
  for (int c=0;c<M_;c++) rsm += fabsf(Ab[(size_t)t*M_ + c]);
  __shared__ float sh[4];
  float v = cs;
  for (int off=32; off; off>>=1) v = fmaxf(v, __shfl_xor(v, off));
  if ((t&63)==0) sh[t>>6] = v;
  __syncthreads();
  float maxc = fmaxf(fmaxf(sh[0],sh[1]), fmaxf(sh[2],sh[3]));
  __syncthreads();
  v = rsm;
  for (int off=32; off; off>>=1) v = fmaxf(v, __shfl_xor(v, off));
  if ((t&63)==0) sh[t>>6] = v;
  __syncthreads();
  float maxr = fmaxf(fmaxf(sh[0],sh[1]), fmaxf(sh[2],sh[3]));
  float inv = 1.f/(maxr*maxc);
  for (int r=0;r<M_;r++) Zb[(size_t)r*M_ + t] = Ab[(size_t)t*M_ + r]*inv;
}

// ---------------- pinv GEMM 256x256x256 fp32, fused: C = cScale*(cNeg? cDiag*I - A@B' : A@B'), B' = bNeg? bDiag*I-B : B
__global__ __launch_bounds__(256) void k_gemm_pf(float* __restrict__ C, const float* __restrict__ A,
    const float* __restrict__ Bm, float bDiag, int bNeg, float cDiag, int cNeg, float cScale){
  int bh = blockIdx.y;
  int tm = blockIdx.x >> 2, tn = blockIdx.x & 3;
  const float* Ab = A  + (size_t)bh*65536;
  const float* Bb = Bm + (size_t)bh*65536;
  float* Cb = C + (size_t)bh*65536;
  __shared__ float As[16][68];
  __shared__ float Bs[16][64];
  int t = threadIdx.x, tx = t&15, ty = t>>4;
  int r0 = tm*64, c0 = tn*64;
  float acc[4][4] = {};
  for (int k0=0;k0<256;k0+=16){
    for (int i=t;i<1024;i+=256){
      int m=i>>4, kq=i&15;
      As[kq][m] = Ab[(size_t)(r0+m)*256 + k0+kq];
      int nn=i&63, k2=i>>6;
      float bval = Bb[(size_t)(k0+k2)*256 + c0+nn];
      if (bNeg) bval = ((k0+k2)==(c0+nn) ? bDiag : 0.f) - bval;
      Bs[k2][nn] = bval;
    }
    __syncthreads();
    #pragma unroll
    for (int kq=0;kq<16;kq++){
      float a0[4], b0[4];
      #pragma unroll
      for (int i=0;i<4;i++) a0[i] = As[kq][ty*4+i];
      #pragma unroll
      for (int j=0;j<4;j++) b0[j] = Bs[kq][tx*4+j];
      #pragma unroll
      for (int i=0;i<4;i++)
        #pragma unroll
        for (int j=0;j<4;j++) acc[i][j] += a0[i]*b0[j];
    }
    __syncthreads();
  }
  #pragma unroll
  for (int i=0;i<4;i++){
    int r = r0+ty*4+i;
    #pragma unroll
    for (int j=0;j<4;j++){
      int cidx = c0+tx*4+j;
      float r_ = acc[i][j];
      if (cNeg) r_ = ((r==cidx)? cDiag : 0.f) - r_;
      Cb[(size_t)r*256 + cidx] = r_*cScale;
    }
  }
}

// ---------------- batched GEMM 256x64x256: z2T(bf16,[bh][64][256]) = (Z(fp32) @ kv3(bf16))^T ----------------
__global__ __launch_bounds__(256) void k_gemm_z2(bf16* __restrict__ z2t, const float* __restrict__ A,
    const bf16* __restrict__ Bm){
  int bh = blockIdx.y;
  int tm = blockIdx.x;
  const float* Ab = A  + (size_t)bh*65536;
  const bf16* Bb = Bm + (size_t)bh*M_*DH_;
  __shared__ float As[16][68];
  __shared__ float Bs[16][64];
  int t = threadIdx.x, tx = t&15, ty = t>>4;
  int r0 = tm*64;
  float acc[4][4] = {};
  for (int k0=0;k0<256;k0+=16){
    for (int i=t;i<1024;i+=256){
      int m=i>>4, kq=i&15;
      As[kq][m] = Ab[(size_t)(r0+m)*256 + k0+kq];
      int nn=i&63, k2=i>>6;
      Bs[k2][nn] = bf2f(Bb[(size_t)(k0+k2)*64 + nn]);
    }
    __syncthreads();
    #pragma unroll
    for (int kq=0;kq<16;kq++){
      float a0[4], b0[4];
      #pragma unroll
      for (int i=0;i<4;i++) a0[i] = As[kq][ty*4+i];
      #pragma unroll
      for (int j=0;j<4;j++) b0[j] = Bs[kq][tx*4+j];
      #pragma unroll
      for (int i=0;i<4;i++)
        #pragma unroll
        for (int j=0;j<4;j++) acc[i][j] += a0[i]*b0[j];
    }
    __syncthreads();
  }
  #pragma unroll
  for (int i=0;i<4;i++){
    int r = r0+ty*4+i;
    #pragma unroll
    for (int j=0;j<4;j++)
      z2t[(size_t)bh*16384 + (size_t)(tx*4+j)*256 + r] = f2bf(acc[i][j]);
  }
}

// ---------------- flash (MFMA): O = softmax_rows(Q K^T) @ V ----------------
// Q:[bh][nrows][64], K:[bh][ncols][64], VT:[bh][64][ncols], O:[bh][nrows][64]
// block: 16 Q-rows, 4 waves, wave w handles col chunk [w*ncols/4,(w+1)*ncols/4), merged in LDS.
__global__ __launch_bounds__(256) void k_flash(const bf16* __restrict__ Q, const bf16* __restrict__ K,
    const bf16* __restrict__ VT, bf16* __restrict__ O, int nrows, int ncols){
  int bh = blockIdx.y;
  int r0 = blockIdx.x * 16;
  int t = threadIdx.x, w = t>>6, lane = t&63, qd = lane>>4, n = lane&15;
  int chunk = ncols >> 2;
  int cbase = w * chunk;
  const size_t Qoff = ((size_t)bh*nrows + r0)*DH_;
  const size_t Koff = (size_t)bh*(size_t)ncols*DH_;
  const size_t Voff = (size_t)bh*DH_*(size_t)ncols;
  __shared__ __align__(16) bf16 pbuf[4][16][40];
  __shared__ float obuf[4][16][64];
  __shared__ float mbuf[4][16];
  __shared__ float lbuf[4][16];
  short8 aq0 = *(const short8*)&Q[Qoff + (size_t)n*DH_ + qd*8];
  short8 aq1 = *(const short8*)&Q[Qoff + (size_t)n*DH_ + 32 + qd*8];
  f32x4 o0 = {0.f,0.f,0.f,0.f}, o1 = o0, o2 = o0, o3 = o0;
  float mrun[4] = {-1e30f,-1e30f,-1e30f,-1e30f};
  float lrun[4] = {0.f,0.f,0.f,0.f};
  int ntiles = chunk >> 5;
  for (int tl=0; tl<ntiles; ++tl){
    int col0 = cbase + tl*32;
    const bf16* kp = K + Koff + (size_t)col0*DH_;
    short8 b00 = *(const short8*)&kp[(size_t)n*DH_ + qd*8];
    short8 b01 = *(const short8*)&kp[(size_t)n*DH_ + 32 + qd*8];
    short8 b10 = *(const short8*)&kp[(size_t)(16+n)*DH_ + qd*8];
    short8 b11 = *(const short8*)&kp[(size_t)(16+n)*DH_ + 32 + qd*8];
    f32x4 s0 = {0.f,0.f,0.f,0.f}, s1 = {0.f,0.f,0.f,0.f};
    s0 = mfma16(aq0, b00, s0); s0 = mfma16(aq1, b01, s0);
    s1 = mfma16(aq0, b10, s1); s1 = mfma16(aq1, b11, s1);
    float alpha[4];
    #pragma unroll
    for (int rg=0; rg<4; rg++){
      float tmax = fmaxf(s0[rg], s1[rg]);
      tmax = fmaxf(tmax, __shfl_xor(tmax, 1));
      tmax = fmaxf(tmax, __shfl_xor(tmax, 2));
      tmax = fmaxf(tmax, __shfl_xor(tmax, 4));
      tmax = fmaxf(tmax, __shfl_xor(tmax, 8));
      float mn = fmaxf(mrun[rg], tmax);
      float p0 = __expf(s0[rg]-mn), p1 = __expf(s1[rg]-mn);
      float ts = p0 + p1;
      ts += __shfl_xor(ts,1); ts += __shfl_xor(ts,2); ts += __shfl_xor(ts,4); ts += __shfl_xor(ts,8);
      float al = __expf(mrun[rg]-mn);
      lrun[rg] = lrun[rg]*al + ts;
      mrun[rg] = mn;
      alpha[rg] = al;
      pbuf[w][qd*4+rg][n]    = f2bf(p0);
      pbuf[w][qd*4+rg][16+n] = f2bf(p1);
    }
    short8 ap = *(const short8*)&pbuf[w][n][qd*8];   // wave-synchronous LDS transpose (C->A layout)
    #pragma unroll
    for (int rg=0; rg<4; rg++){ o0[rg]*=alpha[rg]; o1[rg]*=alpha[rg]; o2[rg]*=alpha[rg]; o3[rg]*=alpha[rg]; }
    const bf16* vp = VT + Voff + col0 + qd*8;
    short8 bv0 = *(const short8*)&vp[(size_t)n*ncols];
    short8 bv1 = *(const short8*)&vp[(size_t)(16+n)*ncols];
    short8 bv2 = *(const short8*)&vp[(size_t)(32+n)*ncols];
    short8 bv3 = *(const short8*)&vp[(size_t)(48+n)*ncols];
    o0 = mfma16(ap, bv0, o0); o1 = mfma16(ap, bv1, o1);
    o2 = mfma16(ap, bv2, o2); o3 = mfma16(ap, bv3, o3);
  }
  #pragma unroll
  for (int rg=0; rg<4; rg++){
    obuf[w][qd*4+rg][n]    = o0[rg];
    obuf[w][qd*4+rg][16+n] = o1[rg];
    obuf[w][qd*4+rg][32+n] = o2[rg];
    obuf[w][qd*4+rg][48+n] = o3[rg];
  }
  if (n==0){
    #pragma unroll
    for (int rg=0; rg<4; rg++){ mbuf[w][qd*4+rg]=mrun[rg]; lbuf[w][qd*4+rg]=lrun[rg]; }
  }
  __syncthreads();
  for (int i=t; i<1024; i+=256){
    int row = i>>6, dh = i&63;
    float m0=mbuf[0][row], m1=mbuf[1][row], m2=mbuf[2][row], m3=mbuf[3][row];
    float M = fmaxf(fmaxf(m0,m1),fmaxf(m2,m3));
    float w0=__expf(m0-M), w1=__expf(m1-M), w2=__expf(m2-M), w3=__expf(m3-M);
    float denom = w0*lbuf[0][row]+w1*lbuf[1][row]+w2*lbuf[2][row]+w3*lbuf[3][row];
    float val = (w0*obuf[0][row][dh]+w1*obuf[1][row][dh]+w2*obuf[2][row][dh]+w3*obuf[3][row][dh])/denom;
    O[((size_t)bh*nrows + r0 + row)*DH_ + dh] = f2bf(val);
  }
}

// ---------------- depthwise conv(KER=33) over sequence on v, add into outh (bf16 rmw) ----------------
__global__ __launch_bounds__(256) void k_conv_add(const bf16* __restrict__ v, const float* __restrict__ w,
    bf16* __restrict__ outh){
  size_t gid = (size_t)blockIdx.x*256 + threadIdx.x;
  int dh = (int)(gid & 63);
  int nn0 = (int)((gid >> 6) & (size_t)(N_-1));
  int bh = (int)(gid >> 19);
  int h = bh & 7;
  __shared__ float wk[KER_];
  if (threadIdx.x < KER_) wk[threadIdx.x] = w[h*KER_ + threadIdx.x];
  __syncthreads();
  const bf16* vb = v + (size_t)bh*N_*DH_;
  float acc = bf2f(outh[gid]);
  #pragma unroll
  for (int tt=0; tt<KER_; tt++){
    int nn = nn0 + tt - 16;
    if (nn >= 0 && nn < N_) acc += wk[tt]*bf2f(vb[(size_t)nn*DH_ + dh]);
  }
  outh[gid] = f2bf(acc);
}

// ---------------- final GEMM (MFMA): out = x + gather(outh) @ w_out + b_out (fp32 out) ----------------
__global__ __launch_bounds__(256) void k_mm_out(const bf16* __restrict__ Ah, const float* __restrict__ W,
    const float* __restrict__ bias, const float* __restrict__ xin, float* __restrict__ out){
  __shared__ __align__(16) bf16 bt[128][40];
  int t = threadIdx.x;
  int w = t>>6, lane = t&63, qd = lane>>4, n = lane&15;
  int r0 = blockIdx.x*64, c0 = blockIdx.y*128;
  int bb = r0 >> 13, nbase = r0 & 8191;
  f32x4 acc[8];
  #pragma unroll
  for (int i=0;i<8;i++) acc[i] = (f32x4){0.f,0.f,0.f,0.f};
  for (int k0=0; k0<512; k0+=32){
    for (int i=t;i<4096;i+=256){
      int kk = i>>7, cc = i&127;
      bt[cc][kk] = f2bf(W[(size_t)(k0+kk)*512 + c0+cc]);
    }
    __syncthreads();
    int h = (k0 + qd*8) >> 6, dh0 = (k0 + qd*8) & 63;
    short8 a = *(const short8*)&Ah[((size_t)(bb*H_+h)*N_ + nbase + w*16 + n)*DH_ + dh0];
    #pragma unroll
    for (int nt=0; nt<8; nt++){
      short8 b = *(const short8*)&bt[nt*16+n][qd*8];
      acc[nt] = mfma16(a, b, acc[nt]);
    }
    __syncthreads();
  }
  #pragma unroll
  for (int nt=0; nt<8; nt++){
    int c = c0 + nt*16 + n;
    #pragma unroll
    for (int rg=0; rg<4; rg++){
      int r = r0 + w*16 + qd*4 + rg;
      out[(size_t)r*512 + c] = acc[nt][rg] + bias[c] + xin[(size_t)r*512 + c];
    }
  }
}

extern "C" void kernel_launch(void* const* d_in, const int* in_sizes, int n_in,
                              void* d_out, int out_size, void* d_ws, size_t ws_size,
                              hipStream_t stream) {
  const float* x     = (const float*)d_in[0];
  const float* gamma = (const float*)d_in[1];
  const float* beta  = (const float*)d_in[2];
  const float* wqkv  = (const float*)d_in[3];
  const float* resk  = (const float*)d_in[4];
  const float* wout  = (const float*)d_in[5];
  const float* bout  = (const float*)d_in[6];
  float* out = (float*)d_out;

  const size_t SL = (size_t)B_*H_*N_*DH_;     // 16,777,216
  const size_t SM = (size_t)B_*H_*M_*DH_;     // 524,288
  const size_t SP = (size_t)B_*H_*M_*M_;      // 2,097,152

  bf16* xn  = (bf16*)d_ws;     // SL; reused as outh; pinv P1..P4 alias this region in between
  bf16* q   = xn + SL;
  bf16* k   = q + SL;
  bf16* v   = k + SL;
  bf16* vT  = v + SL;
  bf16* ql  = vT + SL;
  bf16* kl  = ql + SM;
  bf16* kv3 = kl + SM;
  bf16* z2T = kv3 + SM;
  float* A2 = (float*)(z2T + SM);
  // pinv scratch aliases xn (dead between qkv-consume and flash2-produce): 4*SP*4B == SL*2B exactly
  float* P1 = (float*)xn;
  float* P2 = P1 + SP;
  float* P3 = P2 + SP;
  float* P4 = P3 + SP;

  k_layernorm<<<B_*N_, 256, 0, stream>>>(x, gamma, beta, xn);
  k_mm_qkv<<<dim3(512, 12), 256, 0, stream>>>(xn, wqkv, q, k, v, vT);
  k_landmark<<<B_*H_*M_, 64, 0, stream>>>(q, k, ql, kl);
  k_attn2<<<B_*H_*M_, 256, 0, stream>>>(ql, kl, A2);
  k_pinv_init<<<B_*H_, 256, 0, stream>>>(A2, P1);

  float* Zi = P1; float* Zo = P3;
  for (int it=0; it<6; ++it){
    k_gemm_pf<<<dim3(16,32), 256, 0, stream>>>(P2, A2, Zi, 0.f,0, 0.f,0, 1.f);    // P = A2@Z
    k_gemm_pf<<<dim3(16,32), 256, 0, stream>>>(Zo, P2, P2, 7.f,1, 15.f,1, 1.f);   // S = 15I - P@(7I-P)
    k_gemm_pf<<<dim3(16,32), 256, 0, stream>>>(P4, P2, Zo, 0.f,0, 13.f,1, 1.f);   // U = 13I - P@S
    k_gemm_pf<<<dim3(16,32), 256, 0, stream>>>(Zo, Zi, P4, 0.f,0, 0.f,0, 0.25f);  // Zn = 0.25*Z@U
    float* tt = Zi; Zi = Zo; Zo = tt;
  }

  // kv3 = softmax(q_l k^T) @ v (flash over N)
  k_flash<<<dim3(M_/16, B_*H_), 256, 0, stream>>>(ql, k, vT, kv3, M_, N_);
  // z2T = (pinv(attn2) @ kv3)^T
  k_gemm_z2<<<dim3(4, B_*H_), 256, 0, stream>>>(z2T, Zi, kv3);
  // outh = softmax(q k_l^T) @ z2 (flash over M) -> into xn region
  k_flash<<<dim3(N_/16, B_*H_), 256, 0, stream>>>(q, kl, z2T, xn, N_, M_);
  // + depthwise conv of v
  k_conv_add<<<(int)(SL/256), 256, 0, stream>>>(v, resk, xn);
  // out = x + outh @ w_out + b_out
  k_mm_out<<<dim3(512, 4), 256, 0, stream>>>(xn, wout, bout, x, out);
}

// Round 5
// 1878.082 us; speedup vs baseline: 2.5208x; 1.0372x over previous
//
#include <hip/hip_runtime.h>
#include <hip/hip_bf16.h>

#define B_ 4
#define N_ 8192
#define D_ 512
#define H_ 8
#define DH_ 64
#define M_ 256
#define LCH 32
#define KER_ 33

typedef __hip_bfloat16 bf16;
typedef __attribute__((ext_vector_type(8))) short short8;
typedef __attribute__((ext_vector_type(4))) float f32x4;

__device__ __forceinline__ float bf2f(bf16 h){ return __bfloat162float(h); }
__device__ __forceinline__ bf16 f2bf(float f){ return __float2bfloat16(f); }
__device__ __forceinline__ f32x4 mfma16(short8 a, short8 b, f32x4 c){
  return __builtin_amdgcn_mfma_f32_16x16x32_bf16(a, b, c, 0, 0, 0);
}

// ---------------- LayerNorm: x (b,n,512) fp32 -> xn bf16 ----------------
__global__ __launch_bounds__(256) void k_layernorm(const float* __restrict__ x,
    const float* __restrict__ gamma, const float* __restrict__ beta,
    bf16* __restrict__ xn){
  int row = blockIdx.x;
  const float* xr = x + (size_t)row * D_;
  bf16* o = xn + (size_t)row * D_;
  int t = threadIdx.x;
  float v0 = xr[t], v1 = xr[t+256];
  float s = v0+v1, ss = v0*v0 + v1*v1;
  __shared__ float sh[8];
  for (int off=32; off; off>>=1){ s += __shfl_xor(s,off); ss += __shfl_xor(ss,off); }
  int lane = t&63, wid = t>>6;
  if (lane==0){ sh[wid] = s; sh[wid+4] = ss; }
  __syncthreads();
  float S  = sh[0]+sh[1]+sh[2]+sh[3];
  float SS = sh[4]+sh[5]+sh[6]+sh[7];
  float mu = S*(1.f/D_);
  float var = SS*(1.f/D_) - mu*mu;
  float rs = rsqrtf(var + 1e-5f);
  o[t]     = f2bf((v0-mu)*rs*gamma[t]     + beta[t]);
  o[t+256] = f2bf((v1-mu)*rs*gamma[t+256] + beta[t+256]);
}

// ---------------- W transpose+convert: W (RxC fp32) -> WT (CxR bf16) ----------------
__global__ __launch_bounds__(256) void k_wt(const float* __restrict__ W, bf16* __restrict__ WT,
    int R, int C){
  int c0 = blockIdx.x*64, r0 = blockIdx.y*64;
  __shared__ float tile[64][65];
  int t = threadIdx.x;
  for (int i=t;i<4096;i+=256){ int r=i>>6, c=i&63; tile[r][c] = W[(size_t)(r0+r)*C + c0+c]; }
  __syncthreads();
  for (int i=t;i<512;i+=256){
    int c=i>>3, rg=i&7;
    short8 o;
    #pragma unroll
    for (int j=0;j<8;j++) ((bf16*)&o)[j] = f2bf(tile[rg*8+j][c]);
    *(short8*)&WT[(size_t)(c0+c)*R + r0 + rg*8] = o;
  }
}

// ---------------- QKV GEMM (MFMA, no LDS): xn @ WT^T, scatter q,k,v head-major ----------------
__global__ __launch_bounds__(256) void k_mm_qkv(const bf16* __restrict__ A, const bf16* __restrict__ WT,
    bf16* __restrict__ qbuf, bf16* __restrict__ kbuf, bf16* __restrict__ vbuf){
  int t = threadIdx.x;
  int w = t>>6, lane = t&63, qd = lane>>4, n = lane&15;
  int r0 = blockIdx.x*64, c0 = blockIdx.y*128;
  f32x4 acc[8];
  #pragma unroll
  for (int i=0;i<8;i++) acc[i] = (f32x4){0.f,0.f,0.f,0.f};
  const bf16* arow = A + (size_t)(r0 + w*16 + n)*512;
  for (int k0=0; k0<512; k0+=32){
    short8 a = *(const short8*)&arow[k0 + qd*8];
    #pragma unroll
    for (int nt=0; nt<8; nt++){
      short8 b = *(const short8*)&WT[(size_t)(c0+nt*16+n)*512 + k0 + qd*8];
      acc[nt] = mfma16(a, b, acc[nt]);
    }
  }
  int part = c0 >> 9;
  bf16* dst = (part==0)? qbuf : (part==1)? kbuf : vbuf;
  float scale = (part==0)? 0.125f : 1.f;
  #pragma unroll
  for (int nt=0; nt<8; nt++){
    int c = c0 + nt*16 + n;
    int cc = c & 511, h = cc>>6, dh = cc&63;
    #pragma unroll
    for (int rg=0; rg<4; rg++){
      int r = r0 + w*16 + qd*4 + rg;
      int b = r >> 13, nn = r & 8191;
      dst[(((size_t)(b*H_+h))*N_ + nn)*DH_ + dh] = f2bf(acc[nt][rg]*scale);
    }
  }
}

// ---------------- v -> vT tiled transpose (64x64) ----------------
__global__ __launch_bounds__(256) void k_transp_v(const bf16* __restrict__ v, bf16* __restrict__ vT){
  int bh = blockIdx.y, n0 = blockIdx.x*64;
  __shared__ bf16 tile[64][72];
  const bf16* vb = v + (size_t)bh*N_*DH_;
  int t = threadIdx.x;
  for (int i=t; i<512; i+=256){
    int r = i>>3, cg = i&7;
    *(short8*)&tile[r][cg*8] = *(const short8*)&vb[(size_t)(n0+r)*DH_ + cg*8];
  }
  __syncthreads();
  bf16* ob = vT + (size_t)bh*DH_*N_;
  for (int i=t; i<512; i+=256){
    int dh = i>>3, ng = i&7;
    short8 o;
    #pragma unroll
    for (int j=0;j<8;j++) ((bf16*)&o)[j] = tile[ng*8+j][dh];
    *(short8*)&ob[(size_t)dh*N_ + n0 + ng*8] = o;
  }
}

// ---------------- landmark means over contiguous 32-row chunks ----------------
__global__ __launch_bounds__(64) void k_landmark(const bf16* __restrict__ q, const bf16* __restrict__ k,
    bf16* __restrict__ ql, bf16* __restrict__ kl){
  int bhm = blockIdx.x;
  int bh = bhm >> 8, m = bhm & 255;
  int dh = threadIdx.x;
  const bf16* qp = q + ((size_t)bh*N_ + (size_t)m*LCH)*DH_ + dh;
  const bf16* kp = k + ((size_t)bh*N_ + (size_t)m*LCH)*DH_ + dh;
  float sq=0.f, sk=0.f;
  #pragma unroll
  for (int j=0;j<LCH;j++){ sq += bf2f(qp[(size_t)j*DH_]); sk += bf2f(kp[(size_t)j*DH_]); }
  ql[((size_t)bh*M_ + m)*DH_ + dh] = f2bf(sq*(1.f/LCH));
  kl[((size_t)bh*M_ + m)*DH_ + dh] = f2bf(sk*(1.f/LCH));
}

// ---------------- attn2 = softmax(q_l @ k_l^T) rows (fp32 out) ----------------
__global__ __launch_bounds__(256) void k_attn2(const bf16* __restrict__ ql, const bf16* __restrict__ kl,
    float* __restrict__ A2){
  int bhm = blockIdx.x;
  int bh = bhm >> 8, m = bhm & 255;
  int t = threadIdx.x;
  __shared__ float qrow[64];
  __shared__ float sh[4];
  if (t < 64) qrow[t] = bf2f(ql[((size_t)bh*M_ + m)*DH_ + t]);
  __syncthreads();
  const bf16* krow = kl + ((size_t)bh*M_ + t)*DH_;
  float s = 0.f;
  #pragma unroll
  for (int i=0;i<64;i++) s += qrow[i]*bf2f(krow[i]);
  float mx = s;
  for (int off=32; off; off>>=1) mx = fmaxf(mx, __shfl_xor(mx, off));
  if ((t&63)==0) sh[t>>6] = mx;
  __syncthreads();
  mx = fmaxf(fmaxf(sh[0],sh[1]), fmaxf(sh[2],sh[3]));
  float e = expf(s - mx);
  float sum = e;
  for (int off=32; off; off>>=1) sum += __shfl_xor(sum, off);
  __syncthreads();
  if ((t&63)==0) sh[t>>6] = sum;
  __syncthreads();
  sum = sh[0]+sh[1]+sh[2]+sh[3];
  A2[((size_t)bh*M_ + m)*M_ + t] = e/sum;
}

// ---------------- pinv init: Z = A^T / (max_rowsum * max_colsum) ----------------
__global__ __launch_bounds__(256) void k_pinv_init(const float* __restrict__ A2, float* __restrict__ Z){
  int bh = blockIdx.x;
  int t = threadIdx.x;
  const float* Ab = A2 + (size_t)bh*M_*M_;
  float* Zb = Z + (size_t)bh*M_*M_;
  float cs=0.f, rsm=0.f;
  for (int r=0;r<M_;r++) cs += fabsf(Ab[(size_t)r*M_ + t]);
  for (int c=0;c<M_;c++) rsm += fabsf(Ab[(size_t)t*M_ + c]);
  __shared__ float sh[4];
  float v = cs;
  for (int off=32; off; off>>=1) v = fmaxf(v, __shfl_xor(v, off));
  if ((t&63)==0) sh[t>>6] = v;
  __syncthreads();
  float maxc = fmaxf(fmaxf(sh[0],sh[1]), fmaxf(sh[2],sh[3]));
  __syncthreads();
  v = rsm;
  for (int off=32; off; off>>=1) v = fmaxf(v, __shfl_xor(v, off));
  if ((t&63)==0) sh[t>>6] = v;
  __syncthreads();
  float maxr = fmaxf(fmaxf(sh[0],sh[1]), fmaxf(sh[2],sh[3]));
  float inv = 1.f/(maxr*maxc);
  for (int r=0;r<M_;r++) Zb[(size_t)r*M_ + t] = Ab[(size_t)t*M_ + r]*inv;
}

// ---------------- pinv GEMM 256x256x256 fp32, fused diagonal ops ----------------
__global__ __launch_bounds__(256) void k_gemm_pf(float* __restrict__ C, const float* __restrict__ A,
    const float* __restrict__ Bm, float bDiag, int bNeg, float cDiag, int cNeg, float cScale){
  int bh = blockIdx.y;
  int tm = blockIdx.x >> 2, tn = blockIdx.x & 3;
  const float* Ab = A  + (size_t)bh*65536;
  const float* Bb = Bm + (size_t)bh*65536;
  float* Cb = C + (size_t)bh*65536;
  __shared__ float As[16][68];
  __shared__ float Bs[16][64];
  int t = threadIdx.x, tx = t&15, ty = t>>4;
  int r0 = tm*64, c0 = tn*64;
  float acc[4][4] = {};
  for (int k0=0;k0<256;k0+=16){
    for (int i=t;i<1024;i+=256){
      int m=i>>4, kq=i&15;
      As[kq][m] = Ab[(size_t)(r0+m)*256 + k0+kq];
      int nn=i&63, k2=i>>6;
      float bval = Bb[(size_t)(k0+k2)*256 + c0+nn];
      if (bNeg) bval = ((k0+k2)==(c0+nn) ? bDiag : 0.f) - bval;
      Bs[k2][nn] = bval;
    }
    __syncthreads();
    #pragma unroll
    for (int kq=0;kq<16;kq++){
      float a0[4], b0[4];
      #pragma unroll
      for (int i=0;i<4;i++) a0[i] = As[kq][ty*4+i];
      #pragma unroll
      for (int j=0;j<4;j++) b0[j] = Bs[kq][tx*4+j];
      #pragma unroll
      for (int i=0;i<4;i++)
        #pragma unroll
        for (int j=0;j<4;j++) acc[i][j] += a0[i]*b0[j];
    }
    __syncthreads();
  }
  #pragma unroll
  for (int i=0;i<4;i++){
    int r = r0+ty*4+i;
    #pragma unroll
    for (int j=0;j<4;j++){
      int cidx = c0+tx*4+j;
      float r_ = acc[i][j];
      if (cNeg) r_ = ((r==cidx)? cDiag : 0.f) - r_;
      Cb[(size_t)r*256 + cidx] = r_*cScale;
    }
  }
}

// ---------------- batched GEMM 256x64x256: z2T = (Z @ kv3)^T ----------------
__global__ __launch_bounds__(256) void k_gemm_z2(bf16* __restrict__ z2t, const float* __restrict__ A,
    const bf16* __restrict__ Bm){
  int bh = blockIdx.y;
  int tm = blockIdx.x;
  const float* Ab = A  + (size_t)bh*65536;
  const bf16* Bb = Bm + (size_t)bh*M_*DH_;
  __shared__ float As[16][68];
  __shared__ float Bs[16][64];
  int t = threadIdx.x, tx = t&15, ty = t>>4;
  int r0 = tm*64;
  float acc[4][4] = {};
  for (int k0=0;k0<256;k0+=16){
    for (int i=t;i<1024;i+=256){
      int m=i>>4, kq=i&15;
      As[kq][m] = Ab[(size_t)(r0+m)*256 + k0+kq];
      int nn=i&63, k2=i>>6;
      Bs[k2][nn] = bf2f(Bb[(size_t)(k0+k2)*64 + nn]);
    }
    __syncthreads();
    #pragma unroll
    for (int kq=0;kq<16;kq++){
      float a0[4], b0[4];
      #pragma unroll
      for (int i=0;i<4;i++) a0[i] = As[kq][ty*4+i];
      #pragma unroll
      for (int j=0;j<4;j++) b0[j] = Bs[kq][tx*4+j];
      #pragma unroll
      for (int i=0;i<4;i++)
        #pragma unroll
        for (int j=0;j<4;j++) acc[i][j] += a0[i]*b0[j];
    }
    __syncthreads();
  }
  #pragma unroll
  for (int i=0;i<4;i++){
    int r = r0+ty*4+i;
    #pragma unroll
    for (int j=0;j<4;j++)
      z2t[(size_t)bh*16384 + (size_t)(tx*4+j)*256 + r] = f2bf(acc[i][j]);
  }
}

// ---------------- flash1 (MFMA, col-split 4 waves + merge) ----------------
__global__ __launch_bounds__(256) void k_flash(const bf16* __restrict__ Q, const bf16* __restrict__ K,
    const bf16* __restrict__ VT, bf16* __restrict__ O, int nrows, int ncols){
  int bh = blockIdx.y;
  int r0 = blockIdx.x * 16;
  int t = threadIdx.x, w = t>>6, lane = t&63, qd = lane>>4, n = lane&15;
  int chunk = ncols >> 2;
  int cbase = w * chunk;
  const size_t Qoff = ((size_t)bh*nrows + r0)*DH_;
  const size_t Koff = (size_t)bh*(size_t)ncols*DH_;
  const size_t Voff = (size_t)bh*DH_*(size_t)ncols;
  __shared__ __align__(16) bf16 pbuf[4][16][40];
  __shared__ float obuf[4][16][64];
  __shared__ float mbuf[4][16];
  __shared__ float lbuf[4][16];
  short8 aq0 = *(const short8*)&Q[Qoff + (size_t)n*DH_ + qd*8];
  short8 aq1 = *(const short8*)&Q[Qoff + (size_t)n*DH_ + 32 + qd*8];
  f32x4 o0 = {0.f,0.f,0.f,0.f}, o1 = o0, o2 = o0, o3 = o0;
  float mrun[4] = {-1e30f,-1e30f,-1e30f,-1e30f};
  float lrun[4] = {0.f,0.f,0.f,0.f};
  int ntiles = chunk >> 5;
  for (int tl=0; tl<ntiles; ++tl){
    int col0 = cbase + tl*32;
    const bf16* kp = K + Koff + (size_t)col0*DH_;
    short8 b00 = *(const short8*)&kp[(size_t)n*DH_ + qd*8];
    short8 b01 = *(const short8*)&kp[(size_t)n*DH_ + 32 + qd*8];
    short8 b10 = *(const short8*)&kp[(size_t)(16+n)*DH_ + qd*8];
    short8 b11 = *(const short8*)&kp[(size_t)(16+n)*DH_ + 32 + qd*8];
    f32x4 s0 = {0.f,0.f,0.f,0.f}, s1 = {0.f,0.f,0.f,0.f};
    s0 = mfma16(aq0, b00, s0); s0 = mfma16(aq1, b01, s0);
    s1 = mfma16(aq0, b10, s1); s1 = mfma16(aq1, b11, s1);
    float alpha[4];
    #pragma unroll
    for (int rg=0; rg<4; rg++){
      float tmax = fmaxf(s0[rg], s1[rg]);
      tmax = fmaxf(tmax, __shfl_xor(tmax, 1));
      tmax = fmaxf(tmax, __shfl_xor(tmax, 2));
      tmax = fmaxf(tmax, __shfl_xor(tmax, 4));
      tmax = fmaxf(tmax, __shfl_xor(tmax, 8));
      float mn = fmaxf(mrun[rg], tmax);
      float p0 = __expf(s0[rg]-mn), p1 = __expf(s1[rg]-mn);
      float ts = p0 + p1;
      ts += __shfl_xor(ts,1); ts += __shfl_xor(ts,2); ts += __shfl_xor(ts,4); ts += __shfl_xor(ts,8);
      float al = __expf(mrun[rg]-mn);
      lrun[rg] = lrun[rg]*al + ts;
      mrun[rg] = mn;
      alpha[rg] = al;
      pbuf[w][qd*4+rg][n]    = f2bf(p0);
      pbuf[w][qd*4+rg][16+n] = f2bf(p1);
    }
    short8 ap = *(const short8*)&pbuf[w][n][qd*8];
    #pragma unroll
    for (int rg=0; rg<4; rg++){ o0[rg]*=alpha[rg]; o1[rg]*=alpha[rg]; o2[rg]*=alpha[rg]; o3[rg]*=alpha[rg]; }
    const bf16* vp = VT + Voff + col0 + qd*8;
    short8 bv0 = *(const short8*)&vp[(size_t)n*ncols];
    short8 bv1 = *(const short8*)&vp[(size_t)(16+n)*ncols];
    short8 bv2 = *(const short8*)&vp[(size_t)(32+n)*ncols];
    short8 bv3 = *(const short8*)&vp[(size_t)(48+n)*ncols];
    o0 = mfma16(ap, bv0, o0); o1 = mfma16(ap, bv1, o1);
    o2 = mfma16(ap, bv2, o2); o3 = mfma16(ap, bv3, o3);
  }
  #pragma unroll
  for (int rg=0; rg<4; rg++){
    obuf[w][qd*4+rg][n]    = o0[rg];
    obuf[w][qd*4+rg][16+n] = o1[rg];
    obuf[w][qd*4+rg][32+n] = o2[rg];
    obuf[w][qd*4+rg][48+n] = o3[rg];
  }
  if (n==0){
    #pragma unroll
    for (int rg=0; rg<4; rg++){ mbuf[w][qd*4+rg]=mrun[rg]; lbuf[w][qd*4+rg]=lrun[rg]; }
  }
  __syncthreads();
  for (int i=t; i<1024; i+=256){
    int row = i>>6, dh = i&63;
    float m0=mbuf[0][row], m1=mbuf[1][row], m2=mbuf[2][row], m3=mbuf[3][row];
    float M = fmaxf(fmaxf(m0,m1),fmaxf(m2,m3));
    float w0=__expf(m0-M), w1=__expf(m1-M), w2=__expf(m2-M), w3=__expf(m3-M);
    float denom = w0*lbuf[0][row]+w1*lbuf[1][row]+w2*lbuf[2][row]+w3*lbuf[3][row];
    float val = (w0*obuf[0][row][dh]+w1*obuf[1][row][dh]+w2*obuf[2][row][dh]+w3*obuf[3][row][dh])/denom;
    O[((size_t)bh*nrows + r0 + row)*DH_ + dh] = f2bf(val);
  }
}

// ---------------- flash2 (MFMA, wave-independent 16-row strips) ----------------
__global__ __launch_bounds__(256) void k_flash_w(const bf16* __restrict__ Q, const bf16* __restrict__ K,
    const bf16* __restrict__ VT, bf16* __restrict__ O, int nrows, int ncols){
  int bh = blockIdx.y;
  int t = threadIdx.x, w = t>>6, lane = t&63, qd = lane>>4, n = lane&15;
  int r0 = blockIdx.x*64 + w*16;
  const size_t Qoff = ((size_t)bh*nrows + r0)*DH_;
  const size_t Koff = (size_t)bh*(size_t)ncols*DH_;
  const size_t Voff = (size_t)bh*DH_*(size_t)ncols;
  __shared__ __align__(16) bf16 pbuf[4][16][40];
  short8 aq0 = *(const short8*)&Q[Qoff + (size_t)n*DH_ + qd*8];
  short8 aq1 = *(const short8*)&Q[Qoff + (size_t)n*DH_ + 32 + qd*8];
  f32x4 o0 = {0.f,0.f,0.f,0.f}, o1 = o0, o2 = o0, o3 = o0;
  float mrun[4] = {-1e30f,-1e30f,-1e30f,-1e30f};
  float lrun[4] = {0.f,0.f,0.f,0.f};
  int ntiles = ncols >> 5;
  for (int tl=0; tl<ntiles; ++tl){
    int col0 = tl*32;
    const bf16* kp = K + Koff + (size_t)col0*DH_;
    short8 b00 = *(const short8*)&kp[(size_t)n*DH_ + qd*8];
    short8 b01 = *(const short8*)&kp[(size_t)n*DH_ + 32 + qd*8];
    short8 b10 = *(const short8*)&kp[(size_t)(16+n)*DH_ + qd*8];
    short8 b11 = *(const short8*)&kp[(size_t)(16+n)*DH_ + 32 + qd*8];
    f32x4 s0 = {0.f,0.f,0.f,0.f}, s1 = {0.f,0.f,0.f,0.f};
    s0 = mfma16(aq0, b00, s0); s0 = mfma16(aq1, b01, s0);
    s1 = mfma16(aq0, b10, s1); s1 = mfma16(aq1, b11, s1);
    float alpha[4];
    #pragma unroll
    for (int rg=0; rg<4; rg++){
      float tmax = fmaxf(s0[rg], s1[rg]);
      tmax = fmaxf(tmax, __shfl_xor(tmax, 1));
      tmax = fmaxf(tmax, __shfl_xor(tmax, 2));
      tmax = fmaxf(tmax, __shfl_xor(tmax, 4));
      tmax = fmaxf(tmax, __shfl_xor(tmax, 8));
      float mn = fmaxf(mrun[rg], tmax);
      float p0 = __expf(s0[rg]-mn), p1 = __expf(s1[rg]-mn);
      float ts = p0 + p1;
      ts += __shfl_xor(ts,1); ts += __shfl_xor(ts,2); ts += __shfl_xor(ts,4); ts += __shfl_xor(ts,8);
      float al = __expf(mrun[rg]-mn);
      lrun[rg] = lrun[rg]*al + ts;
      mrun[rg] = mn;
      alpha[rg] = al;
      pbuf[w][qd*4+rg][n]    = f2bf(p0);
      pbuf[w][qd*4+rg][16+n] = f2bf(p1);
    }
    short8 ap = *(const short8*)&pbuf[w][n][qd*8];
    #pragma unroll
    for (int rg=0; rg<4; rg++){ o0[rg]*=alpha[rg]; o1[rg]*=alpha[rg]; o2[rg]*=alpha[rg]; o3[rg]*=alpha[rg]; }
    const bf16* vp = VT + Voff + col0 + qd*8;
    short8 bv0 = *(const short8*)&vp[(size_t)n*ncols];
    short8 bv1 = *(const short8*)&vp[(size_t)(16+n)*ncols];
    short8 bv2 = *(const short8*)&vp[(size_t)(32+n)*ncols];
    short8 bv3 = *(const short8*)&vp[(size_t)(48+n)*ncols];
    o0 = mfma16(ap, bv0, o0); o1 = mfma16(ap, bv1, o1);
    o2 = mfma16(ap, bv2, o2); o3 = mfma16(ap, bv3, o3);
  }
  #pragma unroll
  for (int rg=0; rg<4; rg++){
    float inv = 1.f/lrun[rg];
    size_t rowoff = ((size_t)bh*nrows + r0 + qd*4 + rg)*DH_;
    O[rowoff + n]      = f2bf(o0[rg]*inv);
    O[rowoff + 16 + n] = f2bf(o1[rg]*inv);
    O[rowoff + 32 + n] = f2bf(o2[rg]*inv);
    O[rowoff + 48 + n] = f2bf(o3[rg]*inv);
  }
}

// ---------------- depthwise conv(KER=33), LDS-tiled, vectorized RMW into outh ----------------
#define CCH 256
__global__ __launch_bounds__(256) void k_conv_add(const bf16* __restrict__ v, const float* __restrict__ w,
    bf16* __restrict__ outh){
  int bh = blockIdx.y;
  int n0 = blockIdx.x * CCH;
  int h = bh & 7;
  __shared__ bf16 vs[CCH+32][72];
  __shared__ float wk[KER_];
  int t = threadIdx.x;
  if (t < KER_) wk[t] = w[h*KER_ + t];
  const bf16* vb = v + (size_t)bh*N_*DH_;
  for (int i=t; i<(CCH+32)*8; i+=256){
    int r = i>>3, cg = i&7;
    int nn = n0 - 16 + r;
    short8 val = {0,0,0,0,0,0,0,0};
    if (nn >= 0 && nn < N_) val = *(const short8*)&vb[(size_t)nn*DH_ + cg*8];
    *(short8*)&vs[r][cg*8] = val;
  }
  __syncthreads();
  int dhg = t & 7, rowg = t >> 3;
  bf16* ob = outh + ((size_t)bh*N_ + n0)*DH_;
  #pragma unroll
  for (int rr=0; rr<8; rr++){
    int lr = rowg*8 + rr;
    float acc[8] = {0.f,0.f,0.f,0.f,0.f,0.f,0.f,0.f};
    for (int tt=0; tt<KER_; tt++){
      short8 vv = *(const short8*)&vs[lr+tt][dhg*8];
      float wt = wk[tt];
      #pragma unroll
      for (int j=0;j<8;j++) acc[j] += wt * bf2f(((bf16*)&vv)[j]);
    }
    short8 o = *(short8*)&ob[(size_t)lr*DH_ + dhg*8];
    #pragma unroll
    for (int j=0;j<8;j++) ((bf16*)&o)[j] = f2bf(bf2f(((bf16*)&o)[j]) + acc[j]);
    *(short8*)&ob[(size_t)lr*DH_ + dhg*8] = o;
  }
}

// ---------------- final GEMM (MFMA, no LDS): out = x + gather(outh) @ WT2^T + b_out ----------------
__global__ __launch_bounds__(256) void k_mm_out(const bf16* __restrict__ Ah, const bf16* __restrict__ WT2,
    const float* __restrict__ bias, const float* __restrict__ xin, float* __restrict__ out){
  int t = threadIdx.x;
  int w = t>>6, lane = t&63, qd = lane>>4, n = lane&15;
  int r0 = blockIdx.x*64, c0 = blockIdx.y*128;
  int bb = r0 >> 13, nbase = r0 & 8191;
  f32x4 acc[8];
  #pragma unroll
  for (int i=0;i<8;i++) acc[i] = (f32x4){0.f,0.f,0.f,0.f};
  for (int k0=0; k0<512; k0+=32){
    int h = (k0 + qd*8) >> 6, dh0 = (k0 + qd*8) & 63;
    short8 a = *(const short8*)&Ah[((size_t)(bb*H_+h)*N_ + nbase + w*16 + n)*DH_ + dh0];
    #pragma unroll
    for (int nt=0; nt<8; nt++){
      short8 b = *(const short8*)&WT2[(size_t)(c0+nt*16+n)*512 + k0 + qd*8];
      acc[nt] = mfma16(a, b, acc[nt]);
    }
  }
  #pragma unroll
  for (int nt=0; nt<8; nt++){
    int c = c0 + nt*16 + n;
    #pragma unroll
    for (int rg=0; rg<4; rg++){
      int r = r0 + w*16 + qd*4 + rg;
      out[(size_t)r*512 + c] = acc[nt][rg] + bias[c] + xin[(size_t)r*512 + c];
    }
  }
}

extern "C" void kernel_launch(void* const* d_in, const int* in_sizes, int n_in,
                              void* d_out, int out_size, void* d_ws, size_t ws_size,
                              hipStream_t stream) {
  const float* x     = (const float*)d_in[0];
  const float* gamma = (const float*)d_in[1];
  const float* beta  = (const float*)d_in[2];
  const float* wqkv  = (const float*)d_in[3];
  const float* resk  = (const float*)d_in[4];
  const float* wout  = (const float*)d_in[5];
  const float* bout  = (const float*)d_in[6];
  float* out = (float*)d_out;

  const size_t SL = (size_t)B_*H_*N_*DH_;
  const size_t SM = (size_t)B_*H_*M_*DH_;
  const size_t SP = (size_t)B_*H_*M_*M_;

  bf16* xn  = (bf16*)d_ws;     // reused as outh; pinv P1..P4 alias this region in between
  bf16* q   = xn + SL;
  bf16* k   = q + SL;
  bf16* v   = k + SL;
  bf16* vT  = v + SL;
  bf16* ql  = vT + SL;
  bf16* kl  = ql + SM;
  bf16* kv3 = kl + SM;
  bf16* z2T = kv3 + SM;
  float* A2 = (float*)(z2T + SM);
  bf16* WT  = (bf16*)(A2 + SP);       // 1536 x 512 bf16
  bf16* WT2 = WT + (size_t)1536*512;  // 512 x 512 bf16
  float* P1 = (float*)xn;             // pinv scratch aliases xn (4*SP*4B == SL*2B)
  float* P2 = P1 + SP;
  float* P3 = P2 + SP;
  float* P4 = P3 + SP;

  k_wt<<<dim3(24, 8), 256, 0, stream>>>(wqkv, WT, 512, 1536);
  k_wt<<<dim3(8, 8), 256, 0, stream>>>(wout, WT2, 512, 512);
  k_layernorm<<<B_*N_, 256, 0, stream>>>(x, gamma, beta, xn);
  k_mm_qkv<<<dim3(512, 12), 256, 0, stream>>>(xn, WT, q, k, v);
  k_transp_v<<<dim3(128, 32), 256, 0, stream>>>(v, vT);
  k_landmark<<<B_*H_*M_, 64, 0, stream>>>(q, k, ql, kl);
  k_attn2<<<B_*H_*M_, 256, 0, stream>>>(ql, kl, A2);
  k_pinv_init<<<B_*H_, 256, 0, stream>>>(A2, P1);

  float* Zi = P1; float* Zo = P3;
  for (int it=0; it<6; ++it){
    k_gemm_pf<<<dim3(16,32), 256, 0, stream>>>(P2, A2, Zi, 0.f,0, 0.f,0, 1.f);    // P = A2@Z
    k_gemm_pf<<<dim3(16,32), 256, 0, stream>>>(Zo, P2, P2, 7.f,1, 15.f,1, 1.f);   // S = 15I - P@(7I-P)
    k_gemm_pf<<<dim3(16,32), 256, 0, stream>>>(P4, P2, Zo, 0.f,0, 13.f,1, 1.f);   // U = 13I - P@S
    k_gemm_pf<<<dim3(16,32), 256, 0, stream>>>(Zo, Zi, P4, 0.f,0, 0.f,0, 0.25f);  // Zn = 0.25*Z@U
    float* tt = Zi; Zi = Zo; Zo = tt;
  }

  k_flash<<<dim3(M_/16, B_*H_), 256, 0, stream>>>(ql, k, vT, kv3, M_, N_);
  k_gemm_z2<<<dim3(4, B_*H_), 256, 0, stream>>>(z2T, Zi, kv3);
  k_flash_w<<<dim3(N_/64, B_*H_), 256, 0, stream>>>(q, kl, z2T, xn, N_, M_);
  k_conv_add<<<dim3(N_/CCH, B_*H_), 256, 0, stream>>>(v, resk, xn);
  k_mm_out<<<dim3(512, 4), 256, 0, stream>>>(xn, WT2, bout, x, out);
}

// Round 6
// 1074.848 us; speedup vs baseline: 4.4046x; 1.7473x over previous
//
#include <hip/hip_runtime.h>
#include <hip/hip_bf16.h>

#define B_ 4
#define N_ 8192
#define D_ 512
#define H_ 8
#define DH_ 64
#define M_ 256
#define LCH 32
#define KER_ 33

typedef __hip_bfloat16 bf16;
typedef __attribute__((ext_vector_type(8))) short short8;
typedef __attribute__((ext_vector_type(4))) float f32x4;

__device__ __forceinline__ float bf2f(bf16 h){ return __bfloat162float(h); }
__device__ __forceinline__ bf16 f2bf(float f){ return __float2bfloat16(f); }
__device__ __forceinline__ f32x4 mfma16(short8 a, short8 b, f32x4 c){
  return __builtin_amdgcn_mfma_f32_16x16x32_bf16(a, b, c, 0, 0, 0);
}

// ---------------- LayerNorm: x (b,n,512) fp32 -> xn bf16 ----------------
__global__ __launch_bounds__(256) void k_layernorm(const float* __restrict__ x,
    const float* __restrict__ gamma, const float* __restrict__ beta,
    bf16* __restrict__ xn){
  int row = blockIdx.x;
  const float* xr = x + (size_t)row * D_;
  bf16* o = xn + (size_t)row * D_;
  int t = threadIdx.x;
  float v0 = xr[t], v1 = xr[t+256];
  float s = v0+v1, ss = v0*v0 + v1*v1;
  __shared__ float sh[8];
  for (int off=32; off; off>>=1){ s += __shfl_xor(s,off); ss += __shfl_xor(ss,off); }
  int lane = t&63, wid = t>>6;
  if (lane==0){ sh[wid] = s; sh[wid+4] = ss; }
  __syncthreads();
  float S  = sh[0]+sh[1]+sh[2]+sh[3];
  float SS = sh[4]+sh[5]+sh[6]+sh[7];
  float mu = S*(1.f/D_);
  float var = SS*(1.f/D_) - mu*mu;
  float rs = rsqrtf(var + 1e-5f);
  o[t]     = f2bf((v0-mu)*rs*gamma[t]     + beta[t]);
  o[t+256] = f2bf((v1-mu)*rs*gamma[t+256] + beta[t+256]);
}

// ---------------- W transpose+convert: W (RxC fp32) -> WT (CxR bf16) ----------------
__global__ __launch_bounds__(256) void k_wt(const float* __restrict__ W, bf16* __restrict__ WT,
    int R, int C){
  int c0 = blockIdx.x*64, r0 = blockIdx.y*64;
  __shared__ float tile[64][65];
  int t = threadIdx.x;
  for (int i=t;i<4096;i+=256){ int r=i>>6, c=i&63; tile[r][c] = W[(size_t)(r0+r)*C + c0+c]; }
  __syncthreads();
  for (int i=t;i<512;i+=256){
    int c=i>>3, rg=i&7;
    short8 o;
    #pragma unroll
    for (int j=0;j<8;j++) ((bf16*)&o)[j] = f2bf(tile[rg*8+j][c]);
    *(short8*)&WT[(size_t)(c0+c)*R + r0 + rg*8] = o;
  }
}

// ---------------- QKV GEMM (MFMA, LDS-staged 128x128 tile): xn @ WT^T -> q,k,v ----------------
__global__ __launch_bounds__(256) void k_mm_qkv2(const bf16* __restrict__ A, const bf16* __restrict__ WT,
    bf16* __restrict__ qbuf, bf16* __restrict__ kbuf, bf16* __restrict__ vbuf){
  __shared__ __align__(16) bf16 As[128][72];
  __shared__ __align__(16) bf16 Bs[128][72];
  int t = threadIdx.x;
  int w = t>>6, lane = t&63, qd = lane>>4, n = lane&15;
  int wm = w>>1, wn = w&1;
  int r0 = blockIdx.x*128, c0 = blockIdx.y*128;
  f32x4 acc[4][4];
  #pragma unroll
  for (int i=0;i<4;i++)
    #pragma unroll
    for (int j=0;j<4;j++) acc[i][j] = (f32x4){0.f,0.f,0.f,0.f};
  int srow = t>>3, skc = t&7;
  for (int k0=0; k0<512; k0+=64){
    #pragma unroll
    for (int ch=0; ch<4; ch++){
      int m = ch*32 + srow;
      *(short8*)&As[m][skc*8] = *(const short8*)&A[(size_t)(r0+m)*512 + k0 + skc*8];
      *(short8*)&Bs[m][skc*8] = *(const short8*)&WT[(size_t)(c0+m)*512 + k0 + skc*8];
    }
    __syncthreads();
    #pragma unroll
    for (int ksub=0; ksub<2; ksub++){
      short8 af[4], bfr[4];
      #pragma unroll
      for (int i=0;i<4;i++) af[i]  = *(const short8*)&As[wm*64+i*16+n][ksub*32+qd*8];
      #pragma unroll
      for (int j=0;j<4;j++) bfr[j] = *(const short8*)&Bs[wn*64+j*16+n][ksub*32+qd*8];
      #pragma unroll
      for (int i=0;i<4;i++)
        #pragma unroll
        for (int j=0;j<4;j++) acc[i][j] = mfma16(af[i], bfr[j], acc[i][j]);
    }
    __syncthreads();
  }
  int part = c0 >> 9;
  bf16* dst = (part==0)? qbuf : (part==1)? kbuf : vbuf;
  float scale = (part==0)? 0.125f : 1.f;
  #pragma unroll
  for (int i=0;i<4;i++){
    #pragma unroll
    for (int j=0;j<4;j++){
      int c = c0 + wn*64 + j*16 + n;
      int cc = c & 511, h = cc>>6, dh = cc&63;
      #pragma unroll
      for (int rg=0; rg<4; rg++){
        int r = r0 + wm*64 + i*16 + qd*4 + rg;
        int b = r >> 13, nn = r & 8191;
        dst[(((size_t)(b*H_+h))*N_ + nn)*DH_ + dh] = f2bf(acc[i][j][rg]*scale);
      }
    }
  }
}

// ---------------- v -> vT tiled transpose (64x64) ----------------
__global__ __launch_bounds__(256) void k_transp_v(const bf16* __restrict__ v, bf16* __restrict__ vT){
  int bh = blockIdx.y, n0 = blockIdx.x*64;
  __shared__ bf16 tile[64][72];
  const bf16* vb = v + (size_t)bh*N_*DH_;
  int t = threadIdx.x;
  for (int i=t; i<512; i+=256){
    int r = i>>3, cg = i&7;
    *(short8*)&tile[r][cg*8] = *(const short8*)&vb[(size_t)(n0+r)*DH_ + cg*8];
  }
  __syncthreads();
  bf16* ob = vT + (size_t)bh*DH_*N_;
  for (int i=t; i<512; i+=256){
    int dh = i>>3, ng = i&7;
    short8 o;
    #pragma unroll
    for (int j=0;j<8;j++) ((bf16*)&o)[j] = tile[ng*8+j][dh];
    *(short8*)&ob[(size_t)dh*N_ + n0 + ng*8] = o;
  }
}

// ---------------- landmark means over contiguous 32-row chunks ----------------
__global__ __launch_bounds__(64) void k_landmark(const bf16* __restrict__ q, const bf16* __restrict__ k,
    bf16* __restrict__ ql, bf16* __restrict__ kl){
  int bhm = blockIdx.x;
  int bh = bhm >> 8, m = bhm & 255;
  int dh = threadIdx.x;
  const bf16* qp = q + ((size_t)bh*N_ + (size_t)m*LCH)*DH_ + dh;
  const bf16* kp = k + ((size_t)bh*N_ + (size_t)m*LCH)*DH_ + dh;
  float sq=0.f, sk=0.f;
  #pragma unroll
  for (int j=0;j<LCH;j++){ sq += bf2f(qp[(size_t)j*DH_]); sk += bf2f(kp[(size_t)j*DH_]); }
  ql[((size_t)bh*M_ + m)*DH_ + dh] = f2bf(sq*(1.f/LCH));
  kl[((size_t)bh*M_ + m)*DH_ + dh] = f2bf(sk*(1.f/LCH));
}

// ---------------- attn2 = softmax(q_l @ k_l^T) rows (fp32 out) ----------------
__global__ __launch_bounds__(256) void k_attn2(const bf16* __restrict__ ql, const bf16* __restrict__ kl,
    float* __restrict__ A2){
  int bhm = blockIdx.x;
  int bh = bhm >> 8, m = bhm & 255;
  int t = threadIdx.x;
  __shared__ float qrow[64];
  __shared__ float sh[4];
  if (t < 64) qrow[t] = bf2f(ql[((size_t)bh*M_ + m)*DH_ + t]);
  __syncthreads();
  const bf16* krow = kl + ((size_t)bh*M_ + t)*DH_;
  float s = 0.f;
  #pragma unroll
  for (int i=0;i<64;i++) s += qrow[i]*bf2f(krow[i]);
  float mx = s;
  for (int off=32; off; off>>=1) mx = fmaxf(mx, __shfl_xor(mx, off));
  if ((t&63)==0) sh[t>>6] = mx;
  __syncthreads();
  mx = fmaxf(fmaxf(sh[0],sh[1]), fmaxf(sh[2],sh[3]));
  float e = expf(s - mx);
  float sum = e;
  for (int off=32; off; off>>=1) sum += __shfl_xor(sum, off);
  __syncthreads();
  if ((t&63)==0) sh[t>>6] = sum;
  __syncthreads();
  sum = sh[0]+sh[1]+sh[2]+sh[3];
  A2[((size_t)bh*M_ + m)*M_ + t] = e/sum;
}

// ---------------- pinv init: Z = A^T / (max_rowsum * max_colsum) ----------------
__global__ __launch_bounds__(256) void k_pinv_init(const float* __restrict__ A2, float* __restrict__ Z){
  int bh = blockIdx.x;
  int t = threadIdx.x;
  const float* Ab = A2 + (size_t)bh*M_*M_;
  float* Zb = Z + (size_t)bh*M_*M_;
  float cs=0.f, rsm=0.f;
  for (int r=0;r<M_;r++) cs += fabsf(Ab[(size_t)r*M_ + t]);
  for (int c=0;c<M_;c++) rsm += fabsf(Ab[(size_t)t*M_ + c]);
  __shared__ float sh[4];
  float v = cs;
  for (int off=32; off; off>>=1) v = fmaxf(v, __shfl_xor(v, off));
  if ((t&63)==0) sh[t>>6] = v;
  __syncthreads();
  float maxc = fmaxf(fmaxf(sh[0],sh[1]), fmaxf(sh[2],sh[3]));
  __syncthreads();
  v = rsm;
  for (int off=32; off; off>>=1) v = fmaxf(v, __shfl_xor(v, off));
  if ((t&63)==0) sh[t>>6] = v;
  __syncthreads();
  float maxr = fmaxf(fmaxf(sh[0],sh[1]), fmaxf(sh[2],sh[3]));
  float inv = 1.f/(maxr*maxc);
  for (int r=0;r<M_;r++) Zb[(size_t)r*M_ + t] = Ab[(size_t)t*M_ + r]*inv;
}

// ---------------- pinv GEMM (split-precision bf16 MFMA): fp32-grade accuracy at MFMA rate ----
// C = cScale*(cNeg? cDiag*I - A@B' : A@B'), B' = bNeg? bDiag*I-B : B
// 64x64 tile per block, 4 waves in 2x2, wave tile 32x32, hi/lo bf16 split, 3 MFMAs/product.
__global__ __launch_bounds__(256) void k_gemm_pm(float* __restrict__ C, const float* __restrict__ A,
    const float* __restrict__ Bm, float bDiag, int bNeg, float cDiag, int cNeg, float cScale){
  int bh = blockIdx.y;
  int tm = blockIdx.x >> 2, tn = blockIdx.x & 3;
  const float* Ab = A  + (size_t)bh*65536;
  const float* Bb = Bm + (size_t)bh*65536;
  float* Cb = C + (size_t)bh*65536;
  __shared__ __align__(16) bf16 Ah[64][72];
  __shared__ __align__(16) bf16 Al[64][72];
  __shared__ __align__(16) bf16 Bh[64][72];
  __shared__ __align__(16) bf16 Bl[64][72];
  int t = threadIdx.x;
  int w = t>>6, lane = t&63, qd = lane>>4, n = lane&15;
  int wm = w>>1, wn = w&1;
  int r0 = tm*64, c0 = tn*64;
  f32x4 acc[2][2];
  #pragma unroll
  for (int i=0;i<2;i++)
    #pragma unroll
    for (int j=0;j<2;j++) acc[i][j] = (f32x4){0.f,0.f,0.f,0.f};
  int srow = t>>3, skc = t&7;
  for (int k0=0; k0<256; k0+=64){
    #pragma unroll
    for (int ch=0; ch<2; ch++){
      int m = ch*32 + srow;
      short8 vh, vl;
      const float* ap = &Ab[(size_t)(r0+m)*256 + k0 + skc*8];
      #pragma unroll
      for (int j=0;j<8;j++){
        float x = ap[j];
        bf16 h = f2bf(x);
        ((bf16*)&vh)[j] = h;
        ((bf16*)&vl)[j] = f2bf(x - bf2f(h));
      }
      *(short8*)&Ah[m][skc*8] = vh;
      *(short8*)&Al[m][skc*8] = vl;
      const float* bp = &Bb[(size_t)(k0+m)*256 + c0 + skc*8];
      int kr = k0 + m;
      #pragma unroll
      for (int j=0;j<8;j++){
        float x = bp[j];
        if (bNeg) x = (kr == (c0 + skc*8 + j) ? bDiag : 0.f) - x;
        bf16 h = f2bf(x);
        ((bf16*)&vh)[j] = h;
        ((bf16*)&vl)[j] = f2bf(x - bf2f(h));
      }
      // B stored transposed-by-construction? No: store as [k][nCol] -> need frag [n][k].
      // Instead store row-major [k][n] and read B-frag via k-major: B fragment for MFMA wants
      // B[k][ncol] with lane n = col, qd*8 = k-chunk contiguous in k. Our LDS rows are k-major
      // in global (Bb[k][c]) so we must transpose: write scalar into [c][k] layout.
      #pragma unroll
      for (int j=0;j<8;j++){
        Bh[skc*8+j][m] = ((bf16*)&vh)[j];
        Bl[skc*8+j][m] = ((bf16*)&vl)[j];
      }
    }
    __syncthreads();
    #pragma unroll
    for (int ksub=0; ksub<2; ksub++){
      short8 afh[2], afl[2], bfh[2], bfl[2];
      #pragma unroll
      for (int i=0;i<2;i++){
        afh[i] = *(const short8*)&Ah[wm*32+i*16+n][ksub*32+qd*8];
        afl[i] = *(const short8*)&Al[wm*32+i*16+n][ksub*32+qd*8];
      }
      #pragma unroll
      for (int j=0;j<2;j++){
        bfh[j] = *(const short8*)&Bh[wn*32+j*16+n][ksub*32+qd*8];
        bfl[j] = *(const short8*)&Bl[wn*32+j*16+n][ksub*32+qd*8];
      }
      #pragma unroll
      for (int i=0;i<2;i++)
        #pragma unroll
        for (int j=0;j<2;j++){
          acc[i][j] = mfma16(afl[i], bfh[j], acc[i][j]);
          acc[i][j] = mfma16(afh[i], bfl[j], acc[i][j]);
          acc[i][j] = mfma16(afh[i], bfh[j], acc[i][j]);
        }
    }
    __syncthreads();
  }
  #pragma unroll
  for (int i=0;i<2;i++){
    #pragma unroll
    for (int j=0;j<2;j++){
      int cidx = c0 + wn*32 + j*16 + n;
      #pragma unroll
      for (int rg=0; rg<4; rg++){
        int r = r0 + wm*32 + i*16 + qd*4 + rg;
        float r_ = acc[i][j][rg];
        if (cNeg) r_ = ((r==cidx)? cDiag : 0.f) - r_;
        Cb[(size_t)r*256 + cidx] = r_*cScale;
      }
    }
  }
}

// ---------------- batched GEMM 256x64x256: z2T = (Z @ kv3)^T ----------------
__global__ __launch_bounds__(256) void k_gemm_z2(bf16* __restrict__ z2t, const float* __restrict__ A,
    const bf16* __restrict__ Bm){
  int bh = blockIdx.y;
  int tm = blockIdx.x;
  const float* Ab = A  + (size_t)bh*65536;
  const bf16* Bb = Bm + (size_t)bh*M_*DH_;
  __shared__ float As[16][68];
  __shared__ float Bs[16][64];
  int t = threadIdx.x, tx = t&15, ty = t>>4;
  int r0 = tm*64;
  float acc[4][4] = {};
  for (int k0=0;k0<256;k0+=16){
    for (int i=t;i<1024;i+=256){
      int m=i>>4, kq=i&15;
      As[kq][m] = Ab[(size_t)(r0+m)*256 + k0+kq];
      int nn=i&63, k2=i>>6;
      Bs[k2][nn] = bf2f(Bb[(size_t)(k0+k2)*64 + nn]);
    }
    __syncthreads();
    #pragma unroll
    for (int kq=0;kq<16;kq++){
      float a0[4], b0[4];
      #pragma unroll
      for (int i=0;i<4;i++) a0[i] = As[kq][ty*4+i];
      #pragma unroll
      for (int j=0;j<4;j++) b0[j] = Bs[kq][tx*4+j];
      #pragma unroll
      for (int i=0;i<4;i++)
        #pragma unroll
        for (int j=0;j<4;j++) acc[i][j] += a0[i]*b0[j];
    }
    __syncthreads();
  }
  #pragma unroll
  for (int i=0;i<4;i++){
    int r = r0+ty*4+i;
    #pragma unroll
    for (int j=0;j<4;j++)
      z2t[(size_t)bh*16384 + (size_t)(tx*4+j)*256 + r] = f2bf(acc[i][j]);
  }
}

// ---------------- flash1 (MFMA, col-split 4 waves + merge) ----------------
__global__ __launch_bounds__(256) void k_flash(const bf16* __restrict__ Q, const bf16* __restrict__ K,
    const bf16* __restrict__ VT, bf16* __restrict__ O, int nrows, int ncols){
  int bh = blockIdx.y;
  int r0 = blockIdx.x * 16;
  int t = threadIdx.x, w = t>>6, lane = t&63, qd = lane>>4, n = lane&15;
  int chunk = ncols >> 2;
  int cbase = w * chunk;
  const size_t Qoff = ((size_t)bh*nrows + r0)*DH_;
  const size_t Koff = (size_t)bh*(size_t)ncols*DH_;
  const size_t Voff = (size_t)bh*DH_*(size_t)ncols;
  __shared__ __align__(16) bf16 pbuf[4][16][40];
  __shared__ float obuf[4][16][64];
  __shared__ float mbuf[4][16];
  __shared__ float lbuf[4][16];
  short8 aq0 = *(const short8*)&Q[Qoff + (size_t)n*DH_ + qd*8];
  short8 aq1 = *(const short8*)&Q[Qoff + (size_t)n*DH_ + 32 + qd*8];
  f32x4 o0 = {0.f,0.f,0.f,0.f}, o1 = o0, o2 = o0, o3 = o0;
  float mrun[4] = {-1e30f,-1e30f,-1e30f,-1e30f};
  float lrun[4] = {0.f,0.f,0.f,0.f};
  int ntiles = chunk >> 5;
  for (int tl=0; tl<ntiles; ++tl){
    int col0 = cbase + tl*32;
    const bf16* kp = K + Koff + (size_t)col0*DH_;
    short8 b00 = *(const short8*)&kp[(size_t)n*DH_ + qd*8];
    short8 b01 = *(const short8*)&kp[(size_t)n*DH_ + 32 + qd*8];
    short8 b10 = *(const short8*)&kp[(size_t)(16+n)*DH_ + qd*8];
    short8 b11 = *(const short8*)&kp[(size_t)(16+n)*DH_ + 32 + qd*8];
    f32x4 s0 = {0.f,0.f,0.f,0.f}, s1 = {0.f,0.f,0.f,0.f};
    s0 = mfma16(aq0, b00, s0); s0 = mfma16(aq1, b01, s0);
    s1 = mfma16(aq0, b10, s1); s1 = mfma16(aq1, b11, s1);
    float alpha[4];
    #pragma unroll
    for (int rg=0; rg<4; rg++){
      float tmax = fmaxf(s0[rg], s1[rg]);
      tmax = fmaxf(tmax, __shfl_xor(tmax, 1));
      tmax = fmaxf(tmax, __shfl_xor(tmax, 2));
      tmax = fmaxf(tmax, __shfl_xor(tmax, 4));
      tmax = fmaxf(tmax, __shfl_xor(tmax, 8));
      float mn = fmaxf(mrun[rg], tmax);
      float p0 = __expf(s0[rg]-mn), p1 = __expf(s1[rg]-mn);
      float ts = p0 + p1;
      ts += __shfl_xor(ts,1); ts += __shfl_xor(ts,2); ts += __shfl_xor(ts,4); ts += __shfl_xor(ts,8);
      float al = __expf(mrun[rg]-mn);
      lrun[rg] = lrun[rg]*al + ts;
      mrun[rg] = mn;
      alpha[rg] = al;
      pbuf[w][qd*4+rg][n]    = f2bf(p0);
      pbuf[w][qd*4+rg][16+n] = f2bf(p1);
    }
    short8 ap = *(const short8*)&pbuf[w][n][qd*8];
    #pragma unroll
    for (int rg=0; rg<4; rg++){ o0[rg]*=alpha[rg]; o1[rg]*=alpha[rg]; o2[rg]*=alpha[rg]; o3[rg]*=alpha[rg]; }
    const bf16* vp = VT + Voff + col0 + qd*8;
    short8 bv0 = *(const short8*)&vp[(size_t)n*ncols];
    short8 bv1 = *(const short8*)&vp[(size_t)(16+n)*ncols];
    short8 bv2 = *(const short8*)&vp[(size_t)(32+n)*ncols];
    short8 bv3 = *(const short8*)&vp[(size_t)(48+n)*ncols];
    o0 = mfma16(ap, bv0, o0); o1 = mfma16(ap, bv1, o1);
    o2 = mfma16(ap, bv2, o2); o3 = mfma16(ap, bv3, o3);
  }
  #pragma unroll
  for (int rg=0; rg<4; rg++){
    obuf[w][qd*4+rg][n]    = o0[rg];
    obuf[w][qd*4+rg][16+n] = o1[rg];
    obuf[w][qd*4+rg][32+n] = o2[rg];
    obuf[w][qd*4+rg][48+n] = o3[rg];
  }
  if (n==0){
    #pragma unroll
    for (int rg=0; rg<4; rg++){ mbuf[w][qd*4+rg]=mrun[rg]; lbuf[w][qd*4+rg]=lrun[rg]; }
  }
  __syncthreads();
  for (int i=t; i<1024; i+=256){
    int row = i>>6, dh = i&63;
    float m0=mbuf[0][row], m1=mbuf[1][row], m2=mbuf[2][row], m3=mbuf[3][row];
    float M = fmaxf(fmaxf(m0,m1),fmaxf(m2,m3));
    float w0=__expf(m0-M), w1=__expf(m1-M), w2=__expf(m2-M), w3=__expf(m3-M);
    float denom = w0*lbuf[0][row]+w1*lbuf[1][row]+w2*lbuf[2][row]+w3*lbuf[3][row];
    float val = (w0*obuf[0][row][dh]+w1*obuf[1][row][dh]+w2*obuf[2][row][dh]+w3*obuf[3][row][dh])/denom;
    O[((size_t)bh*nrows + r0 + row)*DH_ + dh] = f2bf(val);
  }
}

// ---------------- flash2 (MFMA, wave-independent 16-row strips) ----------------
__global__ __launch_bounds__(256) void k_flash_w(const bf16* __restrict__ Q, const bf16* __restrict__ K,
    const bf16* __restrict__ VT, bf16* __restrict__ O, int nrows, int ncols){
  int bh = blockIdx.y;
  int t = threadIdx.x, w = t>>6, lane = t&63, qd = lane>>4, n = lane&15;
  int r0 = blockIdx.x*64 + w*16;
  const size_t Qoff = ((size_t)bh*nrows + r0)*DH_;
  const size_t Koff = (size_t)bh*(size_t)ncols*DH_;
  const size_t Voff = (size_t)bh*DH_*(size_t)ncols;
  __shared__ __align__(16) bf16 pbuf[4][16][40];
  short8 aq0 = *(const short8*)&Q[Qoff + (size_t)n*DH_ + qd*8];
  short8 aq1 = *(const short8*)&Q[Qoff + (size_t)n*DH_ + 32 + qd*8];
  f32x4 o0 = {0.f,0.f,0.f,0.f}, o1 = o0, o2 = o0, o3 = o0;
  float mrun[4] = {-1e30f,-1e30f,-1e30f,-1e30f};
  float lrun[4] = {0.f,0.f,0.f,0.f};
  int ntiles = ncols >> 5;
  for (int tl=0; tl<ntiles; ++tl){
    int col0 = tl*32;
    const bf16* kp = K + Koff + (size_t)col0*DH_;
    short8 b00 = *(const short8*)&kp[(size_t)n*DH_ + qd*8];
    short8 b01 = *(const short8*)&kp[(size_t)n*DH_ + 32 + qd*8];
    short8 b10 = *(const short8*)&kp[(size_t)(16+n)*DH_ + qd*8];
    short8 b11 = *(const short8*)&kp[(size_t)(16+n)*DH_ + 32 + qd*8];
    f32x4 s0 = {0.f,0.f,0.f,0.f}, s1 = {0.f,0.f,0.f,0.f};
    s0 = mfma16(aq0, b00, s0); s0 = mfma16(aq1, b01, s0);
    s1 = mfma16(aq0, b10, s1); s1 = mfma16(aq1, b11, s1);
    float alpha[4];
    #pragma unroll
    for (int rg=0; rg<4; rg++){
      float tmax = fmaxf(s0[rg], s1[rg]);
      tmax = fmaxf(tmax, __shfl_xor(tmax, 1));
      tmax = fmaxf(tmax, __shfl_xor(tmax, 2));
      tmax = fmaxf(tmax, __shfl_xor(tmax, 4));
      tmax = fmaxf(tmax, __shfl_xor(tmax, 8));
      float mn = fmaxf(mrun[rg], tmax);
      float p0 = __expf(s0[rg]-mn), p1 = __expf(s1[rg]-mn);
      float ts = p0 + p1;
      ts += __shfl_xor(ts,1); ts += __shfl_xor(ts,2); ts += __shfl_xor(ts,4); ts += __shfl_xor(ts,8);
      float al = __expf(mrun[rg]-mn);
      lrun[rg] = lrun[rg]*al + ts;
      mrun[rg] = mn;
      alpha[rg] = al;
      pbuf[w][qd*4+rg][n]    = f2bf(p0);
      pbuf[w][qd*4+rg][16+n] = f2bf(p1);
    }
    short8 ap = *(const short8*)&pbuf[w][n][qd*8];
    #pragma unroll
    for (int rg=0; rg<4; rg++){ o0[rg]*=alpha[rg]; o1[rg]*=alpha[rg]; o2[rg]*=alpha[rg]; o3[rg]*=alpha[rg]; }
    const bf16* vp = VT + Voff + col0 + qd*8;
    short8 bv0 = *(const short8*)&vp[(size_t)n*ncols];
    short8 bv1 = *(const short8*)&vp[(size_t)(16+n)*ncols];
    short8 bv2 = *(const short8*)&vp[(size_t)(32+n)*ncols];
    short8 bv3 = *(const short8*)&vp[(size_t)(48+n)*ncols];
    o0 = mfma16(ap, bv0, o0); o1 = mfma16(ap, bv1, o1);
    o2 = mfma16(ap, bv2, o2); o3 = mfma16(ap, bv3, o3);
  }
  #pragma unroll
  for (int rg=0; rg<4; rg++){
    float inv = 1.f/lrun[rg];
    size_t rowoff = ((size_t)bh*nrows + r0 + qd*4 + rg)*DH_;
    O[rowoff + n]      = f2bf(o0[rg]*inv);
    O[rowoff + 16 + n] = f2bf(o1[rg]*inv);
    O[rowoff + 32 + n] = f2bf(o2[rg]*inv);
    O[rowoff + 48 + n] = f2bf(o3[rg]*inv);
  }
}

// ---------------- depthwise conv(KER=33), LDS-tiled, vectorized RMW into outh ----------------
#define CCH 256
__global__ __launch_bounds__(256) void k_conv_add(const bf16* __restrict__ v, const float* __restrict__ w,
    bf16* __restrict__ outh){
  int bh = blockIdx.y;
  int n0 = blockIdx.x * CCH;
  int h = bh & 7;
  __shared__ bf16 vs[CCH+32][72];
  __shared__ float wk[KER_];
  int t = threadIdx.x;
  if (t < KER_) wk[t] = w[h*KER_ + t];
  const bf16* vb = v + (size_t)bh*N_*DH_;
  for (int i=t; i<(CCH+32)*8; i+=256){
    int r = i>>3, cg = i&7;
    int nn = n0 - 16 + r;
    short8 val = {0,0,0,0,0,0,0,0};
    if (nn >= 0 && nn < N_) val = *(const short8*)&vb[(size_t)nn*DH_ + cg*8];
    *(short8*)&vs[r][cg*8] = val;
  }
  __syncthreads();
  int dhg = t & 7, rowg = t >> 3;
  bf16* ob = outh + ((size_t)bh*N_ + n0)*DH_;
  #pragma unroll
  for (int rr=0; rr<8; rr++){
    int lr = rowg*8 + rr;
    float acc[8] = {0.f,0.f,0.f,0.f,0.f,0.f,0.f,0.f};
    for (int tt=0; tt<KER_; tt++){
      short8 vv = *(const short8*)&vs[lr+tt][dhg*8];
      float wt = wk[tt];
      #pragma unroll
      for (int j=0;j<8;j++) acc[j] += wt * bf2f(((bf16*)&vv)[j]);
    }
    short8 o = *(short8*)&ob[(size_t)lr*DH_ + dhg*8];
    #pragma unroll
    for (int j=0;j<8;j++) ((bf16*)&o)[j] = f2bf(bf2f(((bf16*)&o)[j]) + acc[j]);
    *(short8*)&ob[(size_t)lr*DH_ + dhg*8] = o;
  }
}

// ---------------- final GEMM (MFMA, LDS-staged): out = x + gather(outh) @ WT2^T + b_out ----------------
__global__ __launch_bounds__(256) void k_mm_out2(const bf16* __restrict__ Ahd, const bf16* __restrict__ WT2,
    const float* __restrict__ bias, const float* __restrict__ xin, float* __restrict__ out){
  __shared__ __align__(16) bf16 As[128][72];
  __shared__ __align__(16) bf16 Bs[128][72];
  int t = threadIdx.x;
  int w = t>>6, lane = t&63, qd = lane>>4, n = lane&15;
  int wm = w>>1, wn = w&1;
  int r0 = blockIdx.x*128, c0 = blockIdx.y*128;
  f32x4 acc[4][4];
  #pragma unroll
  for (int i=0;i<4;i++)
    #pragma unroll
    for (int j=0;j<4;j++) acc[i][j] = (f32x4){0.f,0.f,0.f,0.f};
  int srow = t>>3, skc = t&7;
  for (int k0=0; k0<512; k0+=64){
    int h = k0 >> 6;
    #pragma unroll
    for (int ch=0; ch<4; ch++){
      int m = ch*32 + srow;
      int r = r0 + m, b = r>>13, nn = r&8191;
      *(short8*)&As[m][skc*8] = *(const short8*)&Ahd[((size_t)(b*H_+h)*N_ + nn)*DH_ + skc*8];
      *(short8*)&Bs[m][skc*8] = *(const short8*)&WT2[(size_t)(c0+m)*512 + k0 + skc*8];
    }
    __syncthreads();
    #pragma unroll
    for (int ksub=0; ksub<2; ksub++){
      short8 af[4], bfr[4];
      #pragma unroll
      for (int i=0;i<4;i++) af[i]  = *(const short8*)&As[wm*64+i*16+n][ksub*32+qd*8];
      #pragma unroll
      for (int j=0;j<4;j++) bfr[j] = *(const short8*)&Bs[wn*64+j*16+n][ksub*32+qd*8];
      #pragma unroll
      for (int i=0;i<4;i++)
        #pragma unroll
        for (int j=0;j<4;j++) acc[i][j] = mfma16(af[i], bfr[j], acc[i][j]);
    }
    __syncthreads();
  }
  #pragma unroll
  for (int i=0;i<4;i++){
    #pragma unroll
    for (int j=0;j<4;j++){
      int c = c0 + wn*64 + j*16 + n;
      #pragma unroll
      for (int rg=0; rg<4; rg++){
        int r = r0 + wm*64 + i*16 + qd*4 + rg;
        out[(size_t)r*512 + c] = acc[i][j][rg] + bias[c] + xin[(size_t)r*512 + c];
      }
    }
  }
}

extern "C" void kernel_launch(void* const* d_in, const int* in_sizes, int n_in,
                              void* d_out, int out_size, void* d_ws, size_t ws_size,
                              hipStream_t stream) {
  const float* x     = (const float*)d_in[0];
  const float* gamma = (const float*)d_in[1];
  const float* beta  = (const float*)d_in[2];
  const float* wqkv  = (const float*)d_in[3];
  const float* resk  = (const float*)d_in[4];
  const float* wout  = (const float*)d_in[5];
  const float* bout  = (const float*)d_in[6];
  float* out = (float*)d_out;

  const size_t SL = (size_t)B_*H_*N_*DH_;
  const size_t SM = (size_t)B_*H_*M_*DH_;
  const size_t SP = (size_t)B_*H_*M_*M_;

  bf16* xn  = (bf16*)d_ws;     // reused as outh; pinv P1..P4 alias this region in between
  bf16* q   = xn + SL;
  bf16* k   = q + SL;
  bf16* v   = k + SL;
  bf16* vT  = v + SL;
  bf16* ql  = vT + SL;
  bf16* kl  = ql + SM;
  bf16* kv3 = kl + SM;
  bf16* z2T = kv3 + SM;
  float* A2 = (float*)(z2T + SM);
  bf16* WT  = (bf16*)(A2 + SP);       // 1536 x 512 bf16
  bf16* WT2 = WT + (size_t)1536*512;  // 512 x 512 bf16
  float* P1 = (float*)xn;             // pinv scratch aliases xn (4*SP*4B == SL*2B)
  float* P2 = P1 + SP;
  float* P3 = P2 + SP;
  float* P4 = P3 + SP;

  k_wt<<<dim3(24, 8), 256, 0, stream>>>(wqkv, WT, 512, 1536);
  k_wt<<<dim3(8, 8), 256, 0, stream>>>(wout, WT2, 512, 512);
  k_layernorm<<<B_*N_, 256, 0, stream>>>(x, gamma, beta, xn);
  k_mm_qkv2<<<dim3(256, 12), 256, 0, stream>>>(xn, WT, q, k, v);
  k_transp_v<<<dim3(128, 32), 256, 0, stream>>>(v, vT);
  k_landmark<<<B_*H_*M_, 64, 0, stream>>>(q, k, ql, kl);
  k_attn2<<<B_*H_*M_, 256, 0, stream>>>(ql, kl, A2);
  k_pinv_init<<<B_*H_, 256, 0, stream>>>(A2, P1);

  float* Zi = P1; float* Zo = P3;
  for (int it=0; it<6; ++it){
    k_gemm_pm<<<dim3(16,32), 256, 0, stream>>>(P2, A2, Zi, 0.f,0, 0.f,0, 1.f);    // P = A2@Z
    k_gemm_pm<<<dim3(16,32), 256, 0, stream>>>(Zo, P2, P2, 7.f,1, 15.f,1, 1.f);   // S = 15I - P@(7I-P)
    k_gemm_pm<<<dim3(16,32), 256, 0, stream>>>(P4, P2, Zo, 0.f,0, 13.f,1, 1.f);   // U = 13I - P@S
    k_gemm_pm<<<dim3(16,32), 256, 0, stream>>>(Zo, Zi, P4, 0.f,0, 0.f,0, 0.25f);  // Zn = 0.25*Z@U
    float* tt = Zi; Zi = Zo; Zo = tt;
  }

  k_flash<<<dim3(M_/16, B_*H_), 256, 0, stream>>>(ql, k, vT, kv3, M_, N_);
  k_gemm_z2<<<dim3(4, B_*H_), 256, 0, stream>>>(z2T, Zi, kv3);
  k_flash_w<<<dim3(N_/64, B_*H_), 256, 0, stream>>>(q, kl, z2T, xn, N_, M_);
  k_conv_add<<<dim3(N_/CCH, B_*H_), 256, 0, stream>>>(v, resk, xn);
  k_mm_out2<<<dim3(256, 4), 256, 0, stream>>>(xn, WT2, bout, x, out);
}